// Round 1
// baseline (290.434 us; speedup 1.0000x reference)
//
#include <hip/hip_runtime.h>
#include <hip/hip_bf16.h>
#include <math.h>

// Problem constants
#define BATCH 32
#define CH_IN 3
#define CH_OUT 8
#define IMG 512
#define KSZ 7
#define CONV_OUT 506          // 512 - 6
#define KPTS 16

// Conv tiling
#define CT_W 64
#define CT_H 32
#define TILES_X 8             // ceil(506/64)
#define TILES_Y 16            // ceil(506/32)
#define TILES_PER_B (TILES_X * TILES_Y)   // 128

// ---------------------------------------------------------------------------
// Kernel 0: transpose conv weights [8][3][7][7] -> [3][7][7][8] for contiguous
// scalar loads in the conv inner loop.
// ---------------------------------------------------------------------------
__global__ void transpose_w_kernel(const float* __restrict__ w, float* __restrict__ wt) {
    int idx = threadIdx.x + blockIdx.x * 256;
    if (idx < CH_OUT * CH_IN * KSZ * KSZ) {
        int o = idx / (CH_IN * KSZ * KSZ);
        int rem = idx % (CH_IN * KSZ * KSZ);
        int c = rem / (KSZ * KSZ);
        int r2 = rem % (KSZ * KSZ);
        int ky = r2 / KSZ, kx = r2 % KSZ;
        wt[((c * KSZ + ky) * KSZ + kx) * CH_OUT + o] = w[idx];
    }
}

// ---------------------------------------------------------------------------
// Kernel 1: conv 7x7 (VALID) + bias + relu + masked partial spatial sum.
// Each block: one 64x32 output tile of one batch. Writes partial[b][tile][8].
// ---------------------------------------------------------------------------
__global__ __launch_bounds__(256, 2)
void conv_pool_kernel(const float* __restrict__ x, const float* __restrict__ wt,
                      const float* __restrict__ conv_b, float* __restrict__ partial) {
    __shared__ float xs[CH_IN][CT_H + 6][CT_W + 8];   // 3*38*72 floats = 32.8 KB

    int blk = blockIdx.x;
    int b = blk >> 7;            // / 128
    int tile = blk & 127;
    int tx0 = (tile & 7) * CT_W;
    int ty0 = (tile >> 3) * CT_H;
    int tid = threadIdx.x;

    // stage input tile (with +6 halo) into LDS; zero-fill out of range
    for (int idx = tid; idx < CH_IN * (CT_H + 6) * (CT_W + 6); idx += 256) {
        int c = idx / ((CT_H + 6) * (CT_W + 6));
        int rem = idx - c * (CT_H + 6) * (CT_W + 6);
        int r = rem / (CT_W + 6);
        int col = rem - r * (CT_W + 6);
        int gr = ty0 + r, gc = tx0 + col;
        float v = 0.f;
        if (gr < IMG && gc < IMG)
            v = x[((b * CH_IN + c) * IMG + gr) * IMG + gc];
        xs[c][r][col] = v;
    }
    __syncthreads();

    int row = tid >> 3;          // 0..31 (tile row)
    int grp = tid & 7;           // 8 consecutive output cols per thread
    int colbase = grp * 8;

    float acc[8][CH_OUT];        // [pixel][out channel]
    #pragma unroll
    for (int p = 0; p < 8; ++p)
        #pragma unroll
        for (int o = 0; o < CH_OUT; ++o) acc[p][o] = 0.f;

    for (int c = 0; c < CH_IN; ++c) {
        for (int ky = 0; ky < KSZ; ++ky) {
            float xr[14];
            #pragma unroll
            for (int i = 0; i < 14; ++i) xr[i] = xs[c][row + ky][colbase + i];
            const float* wp = &wt[((c * KSZ + ky) * KSZ) * CH_OUT];
            #pragma unroll
            for (int kx = 0; kx < KSZ; ++kx) {
                #pragma unroll
                for (int o = 0; o < CH_OUT; ++o) {
                    float wv = wp[kx * CH_OUT + o];   // wave-uniform -> s_load
                    #pragma unroll
                    for (int p = 0; p < 8; ++p)
                        acc[p][o] += xr[kx + p] * wv;
                }
            }
        }
    }

    // bias + relu + validity mask + per-thread sum
    int oy = ty0 + row;
    float osum[CH_OUT];
    #pragma unroll
    for (int o = 0; o < CH_OUT; ++o) {
        float bo = conv_b[o];
        float s = 0.f;
        #pragma unroll
        for (int p = 0; p < 8; ++p) {
            int ox = tx0 + colbase + p;
            float v = acc[p][o] + bo;
            v = v > 0.f ? v : 0.f;
            s += (oy < CONV_OUT && ox < CONV_OUT) ? v : 0.f;
        }
        osum[o] = s;
    }

    // wave reduction (64 lanes), then cross-wave via LDS
    #pragma unroll
    for (int o = 0; o < CH_OUT; ++o) {
        #pragma unroll
        for (int off = 32; off > 0; off >>= 1)
            osum[o] += __shfl_xor(osum[o], off, 64);
    }
    __syncthreads();                 // safe to reuse xs
    float* red = (float*)xs;
    int wave = tid >> 6, lane = tid & 63;
    if (lane == 0) {
        #pragma unroll
        for (int o = 0; o < CH_OUT; ++o) red[wave * CH_OUT + o] = osum[o];
    }
    __syncthreads();
    if (tid < CH_OUT) {
        float s = red[tid] + red[CH_OUT + tid] + red[2 * CH_OUT + tid] + red[3 * CH_OUT + tid];
        partial[(b * TILES_PER_B + tile) * CH_OUT + tid] = s;
    }
}

// ---------------------------------------------------------------------------
// Kernel 2: pooled mean + FC -> pred, build TPS system, pivoted LU solve
// (double precision), emit Wmat as float [32][19][2]. One block, 64 threads.
// ---------------------------------------------------------------------------
__device__ __forceinline__ double ctrl_lin(int i) { return -1.0 + (2.0 / 3.0) * i; }

__global__ void solve_kernel(const float* __restrict__ partial,
                             const float* __restrict__ fc_w,
                             const float* __restrict__ fc_b,
                             float* __restrict__ Wf) {
    __shared__ double L[19][19];
    __shared__ double Ys[19][64];        // columns: b*2 + coord
    __shared__ double piv_fac[19];
    __shared__ int piv_idx;
    __shared__ float pooledS[BATCH][CH_OUT];

    int t = threadIdx.x;                 // 64 threads

    // pooled mean
    for (int p = t; p < BATCH * CH_OUT; p += 64) {
        int b = p >> 3, o = p & 7;
        double s = 0.0;
        for (int tt = 0; tt < TILES_PER_B; ++tt)
            s += (double)partial[(b * TILES_PER_B + tt) * CH_OUT + o];
        pooledS[b][o] = (float)(s / ((double)CONV_OUT * (double)CONV_OUT));
    }
    __syncthreads();

    // FC -> Y (target points), rows 16..18 zero
    {
        int b = t >> 1, c = t & 1;
        for (int k = 0; k < KPTS; ++k) {
            int j = k * 2 + c;
            double s = (double)fc_b[j];
            for (int o = 0; o < CH_OUT; ++o)
                s += (double)pooledS[b][o] * (double)fc_w[j * CH_OUT + o];
            Ys[k][t] = s;
        }
        for (int k = KPTS; k < 19; ++k) Ys[k][t] = 0.0;
    }

    // build L
    for (int p = t; p < 19 * 19; p += 64) {
        int r = p / 19, cc = p % 19;
        double v;
        if (r < KPTS && cc < KPTS) {
            double dx = ctrl_lin(r & 3) - ctrl_lin(cc & 3);
            double dy = ctrl_lin(r >> 2) - ctrl_lin(cc >> 2);
            double d2 = dx * dx + dy * dy;
            v = d2 * log(d2 + 1e-6);
        } else if (r < KPTS) {
            v = (cc == KPTS) ? 1.0 : (cc == KPTS + 1 ? ctrl_lin(r & 3) : ctrl_lin(r >> 2));
        } else if (cc < KPTS) {
            v = (r == KPTS) ? 1.0 : (r == KPTS + 1 ? ctrl_lin(cc & 3) : ctrl_lin(cc >> 2));
        } else v = 0.0;
        L[r][cc] = v;
    }
    __syncthreads();

    // LU with partial pivoting, RHS carried along
    for (int k = 0; k < 19; ++k) {
        if (t == 0) {
            int pi = k; double mx = fabs(L[k][k]);
            for (int i = k + 1; i < 19; ++i) {
                double a = fabs(L[i][k]);
                if (a > mx) { mx = a; pi = i; }
            }
            piv_idx = pi;
        }
        __syncthreads();
        int pi = piv_idx;
        if (pi != k) {
            if (t < 19) { double tmp = L[k][t]; L[k][t] = L[pi][t]; L[pi][t] = tmp; }
            { double tmp = Ys[k][t]; Ys[k][t] = Ys[pi][t]; Ys[pi][t] = tmp; }
        }
        __syncthreads();
        if (t > k && t < 19) piv_fac[t] = L[t][k] / L[k][k];
        __syncthreads();
        if (t > k && t < 19) {
            double lkj = L[k][t];
            for (int i = k + 1; i < 19; ++i) L[i][t] -= piv_fac[i] * lkj;
        }
        {
            double ykt = Ys[k][t];
            for (int i = k + 1; i < 19; ++i) Ys[i][t] -= piv_fac[i] * ykt;
        }
        __syncthreads();
    }

    // back substitution: column t is private to thread t -> no syncs needed
    for (int k = 18; k >= 0; --k) {
        double s = Ys[k][t];
        for (int j = k + 1; j < 19; ++j) s -= L[k][j] * Ys[j][t];
        Ys[k][t] = s / L[k][k];
    }

    // write W as float [b][19][2]
    {
        int b = t >> 1, c = t & 1;
        for (int k = 0; k < 19; ++k)
            Wf[(b * 19 + k) * 2 + c] = (float)Ys[k][t];
    }
}

// ---------------------------------------------------------------------------
// Kernel 3: fused TPS grid evaluation + bilinear grid_sample (zero padding).
// One thread per output pixel; blocks never straddle batches so W loads are
// wave-uniform (scalar).
// ---------------------------------------------------------------------------
__global__ __launch_bounds__(256)
void tps_sample_kernel(const float* __restrict__ x, const float* __restrict__ Wf,
                       float* __restrict__ out) {
    int blk = blockIdx.x;
    int b = blk >> 10;                        // 1024 blocks per batch
    int pix = ((blk & 1023) << 8) | threadIdx.x;
    int i = pix >> 9, j = pix & 511;

    const float* Wb = Wf + b * 38;

    float gx = -1.f + (2.f / 511.f) * (float)j;
    float gy = -1.f + (2.f / 511.f) * (float)i;

    float mx = Wb[32] + gx * Wb[34] + gy * Wb[36];
    float my = Wb[33] + gx * Wb[35] + gy * Wb[37];
    #pragma unroll
    for (int k = 0; k < KPTS; ++k) {
        float sx = -1.f + (2.f / 3.f) * (float)(k & 3);
        float sy = -1.f + (2.f / 3.f) * (float)(k >> 2);
        float dx = gx - sx, dy = gy - sy;
        float d2 = dx * dx + dy * dy;
        float u = d2 * (0.69314718055994531f * __log2f(d2 + 1e-6f));
        mx += u * Wb[2 * k];
        my += u * Wb[2 * k + 1];
    }

    float ix = (mx + 1.f) * 256.f - 0.5f;
    float iy = (my + 1.f) * 256.f - 0.5f;
    float x0f = floorf(ix), y0f = floorf(iy);
    int x0 = (int)x0f, y0 = (int)y0f;
    int x1 = x0 + 1, y1 = y0 + 1;
    float wx1 = ix - x0f, wy1 = iy - y0f;
    float wx0 = 1.f - wx1, wy0 = 1.f - wy1;

    bool vx0 = (x0 >= 0) & (x0 < IMG), vx1 = (x1 >= 0) & (x1 < IMG);
    bool vy0 = (y0 >= 0) & (y0 < IMG), vy1 = (y1 >= 0) & (y1 < IMG);
    int xc0 = min(max(x0, 0), IMG - 1), xc1 = min(max(x1, 0), IMG - 1);
    int yc0 = min(max(y0, 0), IMG - 1), yc1 = min(max(y1, 0), IMG - 1);

    float w00 = (vy0 && vx0) ? wy0 * wx0 : 0.f;
    float w01 = (vy0 && vx1) ? wy0 * wx1 : 0.f;
    float w10 = (vy1 && vx0) ? wy1 * wx0 : 0.f;
    float w11 = (vy1 && vx1) ? wy1 * wx1 : 0.f;

    const float* xb = x + (size_t)b * CH_IN * IMG * IMG;
    int o00 = yc0 * IMG + xc0, o01 = yc0 * IMG + xc1;
    int o10 = yc1 * IMG + xc0, o11 = yc1 * IMG + xc1;

    #pragma unroll
    for (int c = 0; c < CH_IN; ++c) {
        const float* xp = xb + c * (IMG * IMG);
        float v = xp[o00] * w00 + xp[o01] * w01 + xp[o10] * w10 + xp[o11] * w11;
        out[(((size_t)b * CH_IN + c) << 18) + (i << 9) + j] = v;
    }
}

// ---------------------------------------------------------------------------
extern "C" void kernel_launch(void* const* d_in, const int* in_sizes, int n_in,
                              void* d_out, int out_size, void* d_ws, size_t ws_size,
                              hipStream_t stream) {
    const float* x      = (const float*)d_in[0];
    const float* conv_w = (const float*)d_in[1];
    const float* conv_b = (const float*)d_in[2];
    const float* fc_w   = (const float*)d_in[3];
    const float* fc_b   = (const float*)d_in[4];
    float* out = (float*)d_out;

    char* ws = (char*)d_ws;
    float* wt      = (float*)ws;                          // 1176 floats
    float* partial = (float*)(ws + 8192);                 // 32*128*8 floats = 128 KB
    float* Wf      = (float*)(ws + 8192 + 131072);        // 32*19*2 floats

    transpose_w_kernel<<<dim3(5), dim3(256), 0, stream>>>(conv_w, wt);
    conv_pool_kernel<<<dim3(BATCH * TILES_PER_B), dim3(256), 0, stream>>>(x, wt, conv_b, partial);
    solve_kernel<<<dim3(1), dim3(64), 0, stream>>>(partial, fc_w, fc_b, Wf);
    tps_sample_kernel<<<dim3(BATCH * 1024), dim3(256), 0, stream>>>(x, Wf, out);
}

// Round 3
// 289.889 us; speedup vs baseline: 1.0019x; 1.0019x over previous
//
#include <hip/hip_runtime.h>
#include <hip/hip_bf16.h>
#include <hip/hip_fp16.h>
#include <math.h>

// Problem constants
#define BATCH 32
#define CH_IN 3
#define CH_OUT 8
#define IMG 512
#define KSZ 7
#define CONV_OUT 506          // 512 - 6
#define KPTS 16

// Conv tiling
#define CT_W 64
#define CT_H 32
#define TILES_X 8             // ceil(506/64)
#define TILES_Y 16            // ceil(506/32)
#define TILES_PER_B (TILES_X * TILES_Y)   // 128

// f32 -> f16 bits without relying on hip_fp16 helpers
__device__ __forceinline__ unsigned short f2h_bits(float f) {
    _Float16 h = (_Float16)f;
    unsigned short u;
    __builtin_memcpy(&u, &h, 2);
    return u;
}

// ---------------------------------------------------------------------------
// packed f16 dot2 with f32 accumulate: v_dot2_f32_f16 (2x fp32 FLOP rate)
// ---------------------------------------------------------------------------
__device__ __forceinline__ float fdot2(unsigned int a, unsigned int b, float c) {
#if __has_builtin(__builtin_amdgcn_fdot2)
    typedef _Float16 h2 __attribute__((ext_vector_type(2)));
    h2 av, bv;
    __builtin_memcpy(&av, &a, 4);
    __builtin_memcpy(&bv, &b, 4);
    return __builtin_amdgcn_fdot2(av, bv, c, false);
#else
    asm("v_dot2_f32_f16 %0, %1, %2, %0" : "+v"(c) : "v"(a), "v"(b));
    return c;
#endif
}

// ---------------------------------------------------------------------------
// Kernel 0: pack conv weights as half2 kx-pairs: wt2[c][ky][o][q] (uint),
// pair q = (w[2q], w[2q+1]), with w[7] := 0. 3*7*8*4 = 672 words.
// ---------------------------------------------------------------------------
__global__ void wprep_kernel(const float* __restrict__ w, unsigned int* __restrict__ wt2) {
    int idx = threadIdx.x + blockIdx.x * 256;
    if (idx < CH_IN * KSZ * CH_OUT * 4) {
        int q = idx & 3;
        int o = (idx >> 2) & 7;
        int rem = idx >> 5;            // c*7+ky
        int c = rem / KSZ, ky = rem % KSZ;
        int kx0 = 2 * q, kx1 = 2 * q + 1;
        float f0 = w[((o * CH_IN + c) * KSZ + ky) * KSZ + kx0];
        float f1 = (kx1 < KSZ) ? w[((o * CH_IN + c) * KSZ + ky) * KSZ + kx1] : 0.f;
        unsigned int h0 = f2h_bits(f0);
        unsigned int h1 = f2h_bits(f1);
        wt2[idx] = h0 | (h1 << 16);
    }
}

// ---------------------------------------------------------------------------
// Kernel 1: conv 7x7 (VALID) + bias + relu + masked partial spatial sum,
// f16 dot2 inner loop. Each block: one 64x32 output tile of one batch.
// LDS tile stored as half2 pairs: xs_u[c][row][col2], 36 uints (72 px) / row.
// ---------------------------------------------------------------------------
__global__ __launch_bounds__(256, 2)
void conv_pool_kernel(const float* __restrict__ x, const unsigned int* __restrict__ wt2,
                      const float* __restrict__ conv_b, float* __restrict__ partial) {
    __shared__ unsigned int xs_u[CH_IN][CT_H + 6][36];   // 16.4 KB

    int blk = blockIdx.x;
    int b = blk >> 7;            // / 128
    int tile = blk & 127;
    int tx0 = (tile & 7) * CT_W;
    int ty0 = (tile >> 3) * CT_H;
    int tid = threadIdx.x;

    // stage input tile (halo +6) into LDS as packed f16 pairs; zero-fill OOB
    for (int idx = tid; idx < CH_IN * (CT_H + 6) * 36; idx += 256) {
        int c = idx / ((CT_H + 6) * 36);
        int rem = idx - c * ((CT_H + 6) * 36);
        int r = rem / 36;
        int col2 = rem - r * 36;
        int gr = ty0 + r;
        int gc = tx0 + col2 * 2;
        float f0 = 0.f, f1 = 0.f;
        if (gr < IMG) {
            const float* rowp = x + (((size_t)b * CH_IN + c) * IMG + gr) * IMG;
            if (gc < IMG) f0 = rowp[gc];
            if (gc + 1 < IMG) f1 = rowp[gc + 1];
        }
        unsigned int h0 = f2h_bits(f0);
        unsigned int h1 = f2h_bits(f1);
        xs_u[c][r][col2] = h0 | (h1 << 16);
    }
    __syncthreads();

    int row = tid >> 3;          // 0..31 (tile row)
    int grp = tid & 7;           // 8 consecutive output cols per thread

    float acc[8][CH_OUT];        // [pixel][out channel]
    #pragma unroll
    for (int p = 0; p < 8; ++p)
        #pragma unroll
        for (int o = 0; o < CH_OUT; ++o) acc[p][o] = 0.f;

    #pragma unroll
    for (int c = 0; c < CH_IN; ++c) {
        #pragma unroll
        for (int ky = 0; ky < KSZ; ++ky) {
            // strip: 16 px = 8 even-phase pairs, conflict-free b128 x2
            const unsigned int* bp = &xs_u[c][row + ky][grp * 4];
            uint4 lo = *(const uint4*)bp;
            uint4 hi = *(const uint4*)(bp + 4);
            unsigned int E[8] = {lo.x, lo.y, lo.z, lo.w, hi.x, hi.y, hi.z, hi.w};
            unsigned int O[7];
            #pragma unroll
            for (int i = 0; i < 7; ++i)
                O[i] = __builtin_amdgcn_alignbit(E[i + 1], E[i], 16);

            const uint4* wq4 = (const uint4*)&wt2[((c * KSZ + ky) * CH_OUT) * 4];
            #pragma unroll
            for (int o = 0; o < CH_OUT; ++o) {
                uint4 w = wq4[o];      // wave-uniform -> scalar load
                #pragma unroll
                for (int p = 0; p < 8; ++p) {
                    float a = acc[p][o];
                    if (p & 1) {
                        a = fdot2(O[(p >> 1) + 0], w.x, a);
                        a = fdot2(O[(p >> 1) + 1], w.y, a);
                        a = fdot2(O[(p >> 1) + 2], w.z, a);
                        a = fdot2(O[(p >> 1) + 3], w.w, a);
                    } else {
                        a = fdot2(E[(p >> 1) + 0], w.x, a);
                        a = fdot2(E[(p >> 1) + 1], w.y, a);
                        a = fdot2(E[(p >> 1) + 2], w.z, a);
                        a = fdot2(E[(p >> 1) + 3], w.w, a);
                    }
                    acc[p][o] = a;
                }
            }
        }
    }

    // bias + relu + validity mask + per-thread sum
    int oy = ty0 + row;
    int colbase = grp * 8;
    float osum[CH_OUT];
    #pragma unroll
    for (int o = 0; o < CH_OUT; ++o) {
        float bo = conv_b[o];
        float s = 0.f;
        #pragma unroll
        for (int p = 0; p < 8; ++p) {
            int ox = tx0 + colbase + p;
            float v = acc[p][o] + bo;
            v = v > 0.f ? v : 0.f;
            s += (oy < CONV_OUT && ox < CONV_OUT) ? v : 0.f;
        }
        osum[o] = s;
    }

    // wave reduction (64 lanes), then cross-wave via LDS
    #pragma unroll
    for (int o = 0; o < CH_OUT; ++o) {
        #pragma unroll
        for (int off = 32; off > 0; off >>= 1)
            osum[o] += __shfl_xor(osum[o], off, 64);
    }
    __syncthreads();                 // safe to reuse xs
    float* red = (float*)xs_u;
    int wave = tid >> 6, lane = tid & 63;
    if (lane == 0) {
        #pragma unroll
        for (int o = 0; o < CH_OUT; ++o) red[wave * CH_OUT + o] = osum[o];
    }
    __syncthreads();
    if (tid < CH_OUT) {
        float s = red[tid] + red[CH_OUT + tid] + red[2 * CH_OUT + tid] + red[3 * CH_OUT + tid];
        partial[(b * TILES_PER_B + tile) * CH_OUT + tid] = s;
    }
}

// ---------------------------------------------------------------------------
// Kernel 2: pooled mean + FC -> pred, build TPS system, pivoted LU solve
// (double precision), emit Wmat as float [32][19][2]. One block, 64 threads.
// ---------------------------------------------------------------------------
__device__ __forceinline__ double ctrl_lin(int i) { return -1.0 + (2.0 / 3.0) * i; }

__global__ void solve_kernel(const float* __restrict__ partial,
                             const float* __restrict__ fc_w,
                             const float* __restrict__ fc_b,
                             float* __restrict__ Wf) {
    __shared__ double L[19][19];
    __shared__ double Ys[19][64];        // columns: b*2 + coord
    __shared__ double piv_fac[19];
    __shared__ int piv_idx;
    __shared__ float pooledS[BATCH][CH_OUT];

    int t = threadIdx.x;                 // 64 threads

    // pooled mean
    for (int p = t; p < BATCH * CH_OUT; p += 64) {
        int b = p >> 3, o = p & 7;
        double s = 0.0;
        for (int tt = 0; tt < TILES_PER_B; ++tt)
            s += (double)partial[(b * TILES_PER_B + tt) * CH_OUT + o];
        pooledS[b][o] = (float)(s / ((double)CONV_OUT * (double)CONV_OUT));
    }
    __syncthreads();

    // FC -> Y (target points), rows 16..18 zero
    {
        int b = t >> 1, c = t & 1;
        for (int k = 0; k < KPTS; ++k) {
            int j = k * 2 + c;
            double s = (double)fc_b[j];
            for (int o = 0; o < CH_OUT; ++o)
                s += (double)pooledS[b][o] * (double)fc_w[j * CH_OUT + o];
            Ys[k][t] = s;
        }
        for (int k = KPTS; k < 19; ++k) Ys[k][t] = 0.0;
    }

    // build L
    for (int p = t; p < 19 * 19; p += 64) {
        int r = p / 19, cc = p % 19;
        double v;
        if (r < KPTS && cc < KPTS) {
            double dx = ctrl_lin(r & 3) - ctrl_lin(cc & 3);
            double dy = ctrl_lin(r >> 2) - ctrl_lin(cc >> 2);
            double d2 = dx * dx + dy * dy;
            v = d2 * log(d2 + 1e-6);
        } else if (r < KPTS) {
            v = (cc == KPTS) ? 1.0 : (cc == KPTS + 1 ? ctrl_lin(r & 3) : ctrl_lin(r >> 2));
        } else if (cc < KPTS) {
            v = (r == KPTS) ? 1.0 : (r == KPTS + 1 ? ctrl_lin(cc & 3) : ctrl_lin(cc >> 2));
        } else v = 0.0;
        L[r][cc] = v;
    }
    __syncthreads();

    // LU with partial pivoting, RHS carried along
    for (int k = 0; k < 19; ++k) {
        if (t == 0) {
            int pi = k; double mx = fabs(L[k][k]);
            for (int i = k + 1; i < 19; ++i) {
                double a = fabs(L[i][k]);
                if (a > mx) { mx = a; pi = i; }
            }
            piv_idx = pi;
        }
        __syncthreads();
        int pi = piv_idx;
        if (pi != k) {
            if (t < 19) { double tmp = L[k][t]; L[k][t] = L[pi][t]; L[pi][t] = tmp; }
            { double tmp = Ys[k][t]; Ys[k][t] = Ys[pi][t]; Ys[pi][t] = tmp; }
        }
        __syncthreads();
        if (t > k && t < 19) piv_fac[t] = L[t][k] / L[k][k];
        __syncthreads();
        if (t > k && t < 19) {
            double lkj = L[k][t];
            for (int i = k + 1; i < 19; ++i) L[i][t] -= piv_fac[i] * lkj;
        }
        {
            double ykt = Ys[k][t];
            for (int i = k + 1; i < 19; ++i) Ys[i][t] -= piv_fac[i] * ykt;
        }
        __syncthreads();
    }

    // back substitution: column t is private to thread t -> no syncs needed
    for (int k = 18; k >= 0; --k) {
        double s = Ys[k][t];
        for (int j = k + 1; j < 19; ++j) s -= L[k][j] * Ys[j][t];
        Ys[k][t] = s / L[k][k];
    }

    // write W as float [b][19][2]
    {
        int b = t >> 1, c = t & 1;
        for (int k = 0; k < 19; ++k)
            Wf[(b * 19 + k) * 2 + c] = (float)Ys[k][t];
    }
}

// ---------------------------------------------------------------------------
// Kernel 3: fused TPS grid evaluation + bilinear grid_sample (zero padding).
// One thread per output pixel; blocks never straddle batches so W loads are
// wave-uniform (scalar).
// ---------------------------------------------------------------------------
__global__ __launch_bounds__(256)
void tps_sample_kernel(const float* __restrict__ x, const float* __restrict__ Wf,
                       float* __restrict__ out) {
    int blk = blockIdx.x;
    int b = blk >> 10;                        // 1024 blocks per batch
    int pix = ((blk & 1023) << 8) | threadIdx.x;
    int i = pix >> 9, j = pix & 511;

    const float* Wb = Wf + b * 38;

    float gx = -1.f + (2.f / 511.f) * (float)j;
    float gy = -1.f + (2.f / 511.f) * (float)i;

    float mx = Wb[32] + gx * Wb[34] + gy * Wb[36];
    float my = Wb[33] + gx * Wb[35] + gy * Wb[37];
    #pragma unroll
    for (int k = 0; k < KPTS; ++k) {
        float sx = -1.f + (2.f / 3.f) * (float)(k & 3);
        float sy = -1.f + (2.f / 3.f) * (float)(k >> 2);
        float dx = gx - sx, dy = gy - sy;
        float d2 = dx * dx + dy * dy;
        float u = d2 * (0.69314718055994531f * __log2f(d2 + 1e-6f));
        mx += u * Wb[2 * k];
        my += u * Wb[2 * k + 1];
    }

    float ix = (mx + 1.f) * 256.f - 0.5f;
    float iy = (my + 1.f) * 256.f - 0.5f;
    float x0f = floorf(ix), y0f = floorf(iy);
    int x0 = (int)x0f, y0 = (int)y0f;
    int x1 = x0 + 1, y1 = y0 + 1;
    float wx1 = ix - x0f, wy1 = iy - y0f;
    float wx0 = 1.f - wx1, wy0 = 1.f - wy1;

    bool vx0 = (x0 >= 0) & (x0 < IMG), vx1 = (x1 >= 0) & (x1 < IMG);
    bool vy0 = (y0 >= 0) & (y0 < IMG), vy1 = (y1 >= 0) & (y1 < IMG);
    int xc0 = min(max(x0, 0), IMG - 1), xc1 = min(max(x1, 0), IMG - 1);
    int yc0 = min(max(y0, 0), IMG - 1), yc1 = min(max(y1, 0), IMG - 1);

    float w00 = (vy0 && vx0) ? wy0 * wx0 : 0.f;
    float w01 = (vy0 && vx1) ? wy0 * wx1 : 0.f;
    float w10 = (vy1 && vx0) ? wy1 * wx0 : 0.f;
    float w11 = (vy1 && vx1) ? wy1 * wx1 : 0.f;

    const float* xb = x + (size_t)b * CH_IN * IMG * IMG;
    int o00 = yc0 * IMG + xc0, o01 = yc0 * IMG + xc1;
    int o10 = yc1 * IMG + xc0, o11 = yc1 * IMG + xc1;

    #pragma unroll
    for (int c = 0; c < CH_IN; ++c) {
        const float* xp = xb + c * (IMG * IMG);
        float v = xp[o00] * w00 + xp[o01] * w01 + xp[o10] * w10 + xp[o11] * w11;
        out[(((size_t)b * CH_IN + c) << 18) + (i << 9) + j] = v;
    }
}

// ---------------------------------------------------------------------------
extern "C" void kernel_launch(void* const* d_in, const int* in_sizes, int n_in,
                              void* d_out, int out_size, void* d_ws, size_t ws_size,
                              hipStream_t stream) {
    const float* x      = (const float*)d_in[0];
    const float* conv_w = (const float*)d_in[1];
    const float* conv_b = (const float*)d_in[2];
    const float* fc_w   = (const float*)d_in[3];
    const float* fc_b   = (const float*)d_in[4];
    float* out = (float*)d_out;

    char* ws = (char*)d_ws;
    unsigned int* wt2 = (unsigned int*)ws;                // 672 words
    float* partial = (float*)(ws + 8192);                 // 32*128*8 floats = 128 KB
    float* Wf      = (float*)(ws + 8192 + 131072);        // 32*19*2 floats

    wprep_kernel<<<dim3(3), dim3(256), 0, stream>>>(conv_w, wt2);
    conv_pool_kernel<<<dim3(BATCH * TILES_PER_B), dim3(256), 0, stream>>>(x, wt2, conv_b, partial);
    solve_kernel<<<dim3(1), dim3(64), 0, stream>>>(partial, fc_w, fc_b, Wf);
    tps_sample_kernel<<<dim3(BATCH * 1024), dim3(256), 0, stream>>>(x, Wf, out);
}

// Round 4
// 183.952 us; speedup vs baseline: 1.5789x; 1.5759x over previous
//
#include <hip/hip_runtime.h>
#include <hip/hip_bf16.h>
#include <hip/hip_fp16.h>
#include <math.h>

// Problem constants
#define BATCH 32
#define CH_IN 3
#define CH_OUT 8
#define IMG 512
#define KSZ 7
#define CONV_OUT 506          // 512 - 6
#define KPTS 16
#define TILES_PER_B 128       // 32 row-stripes x 4 col-chunks

// Conv MFMA geometry
#define SROWS 23              // 16 out rows + 7 halo (ky pad to 8 -> max n+ky = 22)
#define PITCH_DW 76           // 152 f16 px per row = 304 bytes (16B aligned, good banks)
#define SMEM_DW (CH_IN * SROWS * PITCH_DW)   // 5244 dwords = 21 KB

typedef _Float16 half8_t __attribute__((ext_vector_type(8)));
typedef float f32x4_t __attribute__((ext_vector_type(4)));

__device__ __forceinline__ unsigned short f2h_bits(float f) {
    _Float16 h = (_Float16)f;
    unsigned short u;
    __builtin_memcpy(&u, &h, 2);
    return u;
}

// ---------------------------------------------------------------------------
// Kernel 0: precompute MFMA A-fragment table Afrag[s][lane] (uint4 = 8 f16).
// A[m][k]: m = l&15 = delta*8 + o; k-octet = s*4 + (l>>4) = c*8 + ky; j = kx+delta.
// A[m][k] = w[o][c][ky][j - delta]  (zero outside taps / ky==7 pad row).
// ---------------------------------------------------------------------------
__global__ void wprep_kernel(const float* __restrict__ w, uint4* __restrict__ afrag) {
    int idx = blockIdx.x * 256 + threadIdx.x;
    if (idx >= 6 * 64) return;
    int s = idx >> 6, l = idx & 63;
    int m = l & 15;
    int dlt = m >> 3, o = m & 7;
    int oct = s * 4 + (l >> 4);
    int c = oct >> 3, ky = oct & 7;
    unsigned short h[8];
    #pragma unroll
    for (int j = 0; j < 8; ++j) {
        int kx = j - dlt;
        float v = 0.f;
        if (ky < KSZ && kx >= 0 && kx < KSZ)
            v = w[((o * CH_IN + c) * KSZ + ky) * KSZ + kx];
        h[j] = f2h_bits(v);
    }
    uint4 out;
    __builtin_memcpy(&out, h, 16);
    afrag[idx] = out;
}

// ---------------------------------------------------------------------------
// Kernel 1: conv 7x7 + bias + relu + masked spatial sum via MFMA 16x16x32 f16.
// Block = 16 out rows x 128 out cols of one batch. 4 waves, each 32 cols.
// N-dim = 16 out rows; M-dim = (2 col-shifts x 8 channels); K = 192 = c,ky,kx.
// ---------------------------------------------------------------------------
__global__ __launch_bounds__(256)
void conv_pool_kernel(const float* __restrict__ x, const uint4* __restrict__ afrag,
                      const float* __restrict__ conv_b, float* __restrict__ partial) {
    __shared__ unsigned int smem[SMEM_DW];
    __shared__ float red[4][8];

    int blk = blockIdx.x;
    int b = blk >> 7;
    int stripe = (blk >> 2) & 31;
    int chunk = blk & 3;
    int ybase = stripe * 16;
    int x0 = chunk * 128;
    int tid = threadIdx.x;

    // stage [3][23][152] f16 tile (dword idx == smem idx), zero-fill OOB
    for (int idx = tid; idx < SMEM_DW; idx += 256) {
        int c = idx / (SROWS * PITCH_DW);
        int rem = idx - c * (SROWS * PITCH_DW);
        int r = rem / PITCH_DW;
        int u = rem - r * PITCH_DW;
        int grow = ybase + r, gcol = x0 + 2 * u;
        float f0 = 0.f, f1 = 0.f;
        if (grow < IMG) {
            const float* rp = x + (((size_t)b * CH_IN + c) * IMG + grow) * IMG;
            if (gcol < IMG) f0 = rp[gcol];
            if (gcol + 1 < IMG) f1 = rp[gcol + 1];
        }
        smem[idx] = (unsigned int)f2h_bits(f0) | ((unsigned int)f2h_bits(f1) << 16);
    }
    __syncthreads();

    int l = tid & 63, w = tid >> 6;
    int n = l & 15, g = l >> 4;

    // static A fragments (24 VGPRs)
    uint4 at[6];
    #pragma unroll
    for (int s = 0; s < 6; ++s) at[s] = afrag[s * 64 + l];

    // per-s LDS row base (bytes): row = n + ky of plane c, + wave col offset
    int rowb[6];
    #pragma unroll
    for (int s = 0; s < 6; ++s) {
        int oct = s * 4 + g;
        int c = oct >> 3, ky = oct & 7;
        rowb[s] = (c * SROWS + n + ky) * (PITCH_DW * 4) + w * 64;
    }

    float bias_[4];
    {
        int ob = (g & 1) * 4;
        #pragma unroll
        for (int r2 = 0; r2 < 4; ++r2) bias_[r2] = conv_b[ob + r2];
    }
    bool rowok = (ybase + n) < CONV_OUT;
    int dlt = g >> 1;                 // column shift of this lane's M rows
    float sums[4] = {0.f, 0.f, 0.f, 0.f};
    const char* sb = (const char*)smem;

    #pragma unroll
    for (int u = 0; u < 4; ++u) {     // X8 = x0 + 32w + 8u
        f32x4_t acc[4];
        #pragma unroll
        for (int d = 0; d < 4; ++d) acc[d] = (f32x4_t){0.f, 0.f, 0.f, 0.f};

        #pragma unroll
        for (int s = 0; s < 6; ++s) {
            uint4 lo = *(const uint4*)(sb + rowb[s] + (u << 4));
            uint4 hi = *(const uint4*)(sb + rowb[s] + (u << 4) + 16);
            unsigned int eu[8] = {lo.x, lo.y, lo.z, lo.w, hi.x, hi.y, hi.z, hi.w};
            half8_t a;
            __builtin_memcpy(&a, &at[s], 16);
            #pragma unroll
            for (int d = 0; d < 4; ++d) {
                uint4 bu = make_uint4(eu[d], eu[d + 1], eu[d + 2], eu[d + 3]);
                half8_t bf;
                __builtin_memcpy(&bf, &bu, 16);
                acc[d] = __builtin_amdgcn_mfma_f32_16x16x32_f16(a, bf, acc[d], 0, 0, 0);
            }
        }

        // bias + relu + validity mask + accumulate per-lane channel sums
        #pragma unroll
        for (int d = 0; d < 4; ++d) {
            int col = x0 + 32 * w + 8 * u + 2 * d + dlt;
            bool colok = col < CONV_OUT;
            #pragma unroll
            for (int r2 = 0; r2 < 4; ++r2) {
                float v = acc[d][r2] + bias_[r2];
                v = v > 0.f ? v : 0.f;
                sums[r2] += (rowok && colok) ? v : 0.f;
            }
        }
    }

    // reduce within channel class (lanes sharing bit4), classes = bits {0,1,2,3,5}
    #pragma unroll
    for (int r2 = 0; r2 < 4; ++r2) {
        sums[r2] += __shfl_xor(sums[r2], 1, 64);
        sums[r2] += __shfl_xor(sums[r2], 2, 64);
        sums[r2] += __shfl_xor(sums[r2], 4, 64);
        sums[r2] += __shfl_xor(sums[r2], 8, 64);
        sums[r2] += __shfl_xor(sums[r2], 32, 64);
    }
    if (l == 0) {
        #pragma unroll
        for (int r2 = 0; r2 < 4; ++r2) red[w][r2] = sums[r2];
    }
    if (l == 16) {
        #pragma unroll
        for (int r2 = 0; r2 < 4; ++r2) red[w][4 + r2] = sums[r2];
    }
    __syncthreads();
    if (tid < CH_OUT) {
        float s = red[0][tid] + red[1][tid] + red[2][tid] + red[3][tid];
        partial[(b * TILES_PER_B + stripe * 4 + chunk) * CH_OUT + tid] = s;
    }
}

// ---------------------------------------------------------------------------
// Kernel 2: pooled mean + FC -> pred, TPS system, pivoted LU solve (double),
// emit Wmat as float [32][19][2]. One block, 64 threads.
// ---------------------------------------------------------------------------
__device__ __forceinline__ double ctrl_lin(int i) { return -1.0 + (2.0 / 3.0) * i; }

__global__ void solve_kernel(const float* __restrict__ partial,
                             const float* __restrict__ fc_w,
                             const float* __restrict__ fc_b,
                             float* __restrict__ Wf) {
    __shared__ double L[19][19];
    __shared__ double Ys[19][64];
    __shared__ double piv_fac[19];
    __shared__ int piv_idx;
    __shared__ float pooledS[BATCH][CH_OUT];

    int t = threadIdx.x;

    for (int p = t; p < BATCH * CH_OUT; p += 64) {
        int b = p >> 3, o = p & 7;
        double s = 0.0;
        for (int tt = 0; tt < TILES_PER_B; ++tt)
            s += (double)partial[(b * TILES_PER_B + tt) * CH_OUT + o];
        pooledS[b][o] = (float)(s / ((double)CONV_OUT * (double)CONV_OUT));
    }
    __syncthreads();

    {
        int b = t >> 1, c = t & 1;
        for (int k = 0; k < KPTS; ++k) {
            int j = k * 2 + c;
            double s = (double)fc_b[j];
            for (int o = 0; o < CH_OUT; ++o)
                s += (double)pooledS[b][o] * (double)fc_w[j * CH_OUT + o];
            Ys[k][t] = s;
        }
        for (int k = KPTS; k < 19; ++k) Ys[k][t] = 0.0;
    }

    for (int p = t; p < 19 * 19; p += 64) {
        int r = p / 19, cc = p % 19;
        double v;
        if (r < KPTS && cc < KPTS) {
            double dx = ctrl_lin(r & 3) - ctrl_lin(cc & 3);
            double dy = ctrl_lin(r >> 2) - ctrl_lin(cc >> 2);
            double d2 = dx * dx + dy * dy;
            v = d2 * log(d2 + 1e-6);
        } else if (r < KPTS) {
            v = (cc == KPTS) ? 1.0 : (cc == KPTS + 1 ? ctrl_lin(r & 3) : ctrl_lin(r >> 2));
        } else if (cc < KPTS) {
            v = (r == KPTS) ? 1.0 : (r == KPTS + 1 ? ctrl_lin(cc & 3) : ctrl_lin(cc >> 2));
        } else v = 0.0;
        L[r][cc] = v;
    }
    __syncthreads();

    for (int k = 0; k < 19; ++k) {
        if (t == 0) {
            int pi = k; double mx = fabs(L[k][k]);
            for (int i = k + 1; i < 19; ++i) {
                double a = fabs(L[i][k]);
                if (a > mx) { mx = a; pi = i; }
            }
            piv_idx = pi;
        }
        __syncthreads();
        int pi = piv_idx;
        if (pi != k) {
            if (t < 19) { double tmp = L[k][t]; L[k][t] = L[pi][t]; L[pi][t] = tmp; }
            { double tmp = Ys[k][t]; Ys[k][t] = Ys[pi][t]; Ys[pi][t] = tmp; }
        }
        __syncthreads();
        if (t > k && t < 19) piv_fac[t] = L[t][k] / L[k][k];
        __syncthreads();
        if (t > k && t < 19) {
            double lkj = L[k][t];
            for (int i = k + 1; i < 19; ++i) L[i][t] -= piv_fac[i] * lkj;
        }
        {
            double ykt = Ys[k][t];
            for (int i = k + 1; i < 19; ++i) Ys[i][t] -= piv_fac[i] * ykt;
        }
        __syncthreads();
    }

    for (int k = 18; k >= 0; --k) {
        double s = Ys[k][t];
        for (int j = k + 1; j < 19; ++j) s -= L[k][j] * Ys[j][t];
        Ys[k][t] = s / L[k][k];
    }

    {
        int b = t >> 1, c = t & 1;
        for (int k = 0; k < 19; ++k)
            Wf[(b * 19 + k) * 2 + c] = (float)Ys[k][t];
    }
}

// ---------------------------------------------------------------------------
// Kernel 3: fused TPS grid evaluation + bilinear grid_sample (zero padding).
// ---------------------------------------------------------------------------
__global__ __launch_bounds__(256)
void tps_sample_kernel(const float* __restrict__ x, const float* __restrict__ Wf,
                       float* __restrict__ out) {
    int blk = blockIdx.x;
    int b = blk >> 10;
    int pix = ((blk & 1023) << 8) | threadIdx.x;
    int i = pix >> 9, j = pix & 511;

    const float* Wb = Wf + b * 38;

    float gx = -1.f + (2.f / 511.f) * (float)j;
    float gy = -1.f + (2.f / 511.f) * (float)i;

    float mx = Wb[32] + gx * Wb[34] + gy * Wb[36];
    float my = Wb[33] + gx * Wb[35] + gy * Wb[37];
    #pragma unroll
    for (int k = 0; k < KPTS; ++k) {
        float sx = -1.f + (2.f / 3.f) * (float)(k & 3);
        float sy = -1.f + (2.f / 3.f) * (float)(k >> 2);
        float dx = gx - sx, dy = gy - sy;
        float d2 = dx * dx + dy * dy;
        float u = d2 * (0.69314718055994531f * __log2f(d2 + 1e-6f));
        mx += u * Wb[2 * k];
        my += u * Wb[2 * k + 1];
    }

    float ix = (mx + 1.f) * 256.f - 0.5f;
    float iy = (my + 1.f) * 256.f - 0.5f;
    float x0f = floorf(ix), y0f = floorf(iy);
    int x0 = (int)x0f, y0 = (int)y0f;
    int x1 = x0 + 1, y1 = y0 + 1;
    float wx1 = ix - x0f, wy1 = iy - y0f;
    float wx0 = 1.f - wx1, wy0 = 1.f - wy1;

    bool vx0 = (x0 >= 0) & (x0 < IMG), vx1 = (x1 >= 0) & (x1 < IMG);
    bool vy0 = (y0 >= 0) & (y0 < IMG), vy1 = (y1 >= 0) & (y1 < IMG);
    int xc0 = min(max(x0, 0), IMG - 1), xc1 = min(max(x1, 0), IMG - 1);
    int yc0 = min(max(y0, 0), IMG - 1), yc1 = min(max(y1, 0), IMG - 1);

    float w00 = (vy0 && vx0) ? wy0 * wx0 : 0.f;
    float w01 = (vy0 && vx1) ? wy0 * wx1 : 0.f;
    float w10 = (vy1 && vx0) ? wy1 * wx0 : 0.f;
    float w11 = (vy1 && vx1) ? wy1 * wx1 : 0.f;

    const float* xb = x + (size_t)b * CH_IN * IMG * IMG;
    int o00 = yc0 * IMG + xc0, o01 = yc0 * IMG + xc1;
    int o10 = yc1 * IMG + xc0, o11 = yc1 * IMG + xc1;

    #pragma unroll
    for (int c = 0; c < CH_IN; ++c) {
        const float* xp = xb + c * (IMG * IMG);
        float v = xp[o00] * w00 + xp[o01] * w01 + xp[o10] * w10 + xp[o11] * w11;
        out[(((size_t)b * CH_IN + c) << 18) + (i << 9) + j] = v;
    }
}

// ---------------------------------------------------------------------------
extern "C" void kernel_launch(void* const* d_in, const int* in_sizes, int n_in,
                              void* d_out, int out_size, void* d_ws, size_t ws_size,
                              hipStream_t stream) {
    const float* x      = (const float*)d_in[0];
    const float* conv_w = (const float*)d_in[1];
    const float* conv_b = (const float*)d_in[2];
    const float* fc_w   = (const float*)d_in[3];
    const float* fc_b   = (const float*)d_in[4];
    float* out = (float*)d_out;

    char* ws = (char*)d_ws;
    uint4* afrag   = (uint4*)ws;                          // 6*64*16B = 6 KB
    float* partial = (float*)(ws + 8192);                 // 32*128*8 floats = 128 KB
    float* Wf      = (float*)(ws + 8192 + 131072);        // 32*19*2 floats

    wprep_kernel<<<dim3(2), dim3(256), 0, stream>>>(conv_w, afrag);
    conv_pool_kernel<<<dim3(BATCH * TILES_PER_B), dim3(256), 0, stream>>>(x, afrag, conv_b, partial);
    solve_kernel<<<dim3(1), dim3(64), 0, stream>>>(partial, fc_w, fc_b, Wf);
    tps_sample_kernel<<<dim3(BATCH * 1024), dim3(256), 0, stream>>>(x, Wf, out);
}

// Round 5
// 171.690 us; speedup vs baseline: 1.6916x; 1.0714x over previous
//
#include <hip/hip_runtime.h>
#include <hip/hip_bf16.h>
#include <hip/hip_fp16.h>
#include <math.h>

// Problem constants
#define BATCH 32
#define CH_IN 3
#define CH_OUT 8
#define IMG 512
#define KSZ 7
#define CONV_OUT 506          // 512 - 6
#define KPTS 16
#define TILES_PER_B 128       // 32 row-stripes x 4 col-chunks

// Conv MFMA geometry
#define SROWS 23              // 16 out rows + 7 halo (ky pad to 8 -> max n+ky = 22)
#define PITCH_DW 76           // 152 f16 px per row = 304 bytes (16B aligned, 2-way banks)
#define SMEM_DW (CH_IN * SROWS * PITCH_DW)   // 5244 dwords = 21 KB

typedef _Float16 half8_t __attribute__((ext_vector_type(8)));
typedef float f32x4_t __attribute__((ext_vector_type(4)));

__device__ __forceinline__ unsigned short f2h_bits(float f) {
    _Float16 h = (_Float16)f;
    unsigned short u;
    __builtin_memcpy(&u, &h, 2);
    return u;
}
__device__ __forceinline__ float h2f_bits(unsigned short u) {
    _Float16 h;
    __builtin_memcpy(&h, &u, 2);
    return (float)h;
}

// ---------------------------------------------------------------------------
// Kernel h16: one-pass f32 -> f16 image conversion (memory-bound).
// ---------------------------------------------------------------------------
__global__ __launch_bounds__(256)
void h16_kernel(const float* __restrict__ x, unsigned int* __restrict__ xh) {
    const int total4 = BATCH * CH_IN * IMG * IMG / 4;   // 6291456
    int stride = gridDim.x * 256;
    for (int p = blockIdx.x * 256 + threadIdx.x; p < total4; p += stride) {
        float4 v = ((const float4*)x)[p];
        unsigned int lo = (unsigned int)f2h_bits(v.x) | ((unsigned int)f2h_bits(v.y) << 16);
        unsigned int hi = (unsigned int)f2h_bits(v.z) | ((unsigned int)f2h_bits(v.w) << 16);
        xh[2 * p] = lo;
        xh[2 * p + 1] = hi;
    }
}

// ---------------------------------------------------------------------------
// Kernel 0: precompute MFMA A-fragment table Afrag[s][lane] (uint4 = 8 f16).
// ---------------------------------------------------------------------------
__global__ void wprep_kernel(const float* __restrict__ w, uint4* __restrict__ afrag) {
    int idx = blockIdx.x * 256 + threadIdx.x;
    if (idx >= 6 * 64) return;
    int s = idx >> 6, l = idx & 63;
    int m = l & 15;
    int dlt = m >> 3, o = m & 7;
    int oct = s * 4 + (l >> 4);
    int c = oct >> 3, ky = oct & 7;
    unsigned short h[8];
    #pragma unroll
    for (int j = 0; j < 8; ++j) {
        int kx = j - dlt;
        float v = 0.f;
        if (ky < KSZ && kx >= 0 && kx < KSZ)
            v = w[((o * CH_IN + c) * KSZ + ky) * KSZ + kx];
        h[j] = f2h_bits(v);
    }
    uint4 out;
    __builtin_memcpy(&out, h, 16);
    afrag[idx] = out;
}

// ---------------------------------------------------------------------------
// Kernel 1: conv 7x7 + bias + relu + masked spatial sum via MFMA 16x16x32 f16.
// H16=true: stage from pre-converted f16 image (pure uint4 copy).
// H16=false: fallback, stage from f32 with convert (R4 path).
// ---------------------------------------------------------------------------
template <bool H16>
__global__ __launch_bounds__(256)
void conv_pool_kernel(const float* __restrict__ x, const unsigned short* __restrict__ xh,
                      const uint4* __restrict__ afrag, const float* __restrict__ conv_b,
                      float* __restrict__ partial) {
    __shared__ unsigned int smem[SMEM_DW];
    __shared__ float red[4][8];

    int blk = blockIdx.x;
    int b = blk >> 7;
    int stripe = (blk >> 2) & 31;
    int chunk = blk & 3;
    int ybase = stripe * 16;
    int x0 = chunk * 128;
    int tid = threadIdx.x;

    if (H16) {
        // stage [3][23][152] f16 tile as 16B chunks (19 per row)
        const unsigned short* xhb = xh + (size_t)b * CH_IN * IMG * IMG;
        for (int idx4 = tid; idx4 < SMEM_DW / 4; idx4 += 256) {
            int c = idx4 / (SROWS * 19);
            int rem = idx4 - c * (SROWS * 19);
            int r = rem / 19;
            int u4 = rem - r * 19;
            int grow = ybase + r;
            int gcol = x0 + (u4 << 3);
            uint4 v = make_uint4(0u, 0u, 0u, 0u);
            if (grow < IMG) {
                const unsigned short* rp = xhb + ((size_t)c * IMG + grow) * IMG;
                if (gcol + 8 <= IMG) {
                    v = *(const uint4*)(rp + gcol);
                } else {
                    unsigned short h[8] = {0, 0, 0, 0, 0, 0, 0, 0};
                    #pragma unroll
                    for (int j = 0; j < 8; ++j) {
                        int cc = gcol + j;
                        if (cc < IMG) h[j] = rp[cc];
                    }
                    __builtin_memcpy(&v, h, 16);
                }
            }
            ((uint4*)smem)[idx4] = v;
        }
    } else {
        for (int idx = tid; idx < SMEM_DW; idx += 256) {
            int c = idx / (SROWS * PITCH_DW);
            int rem = idx - c * (SROWS * PITCH_DW);
            int r = rem / PITCH_DW;
            int u = rem - r * PITCH_DW;
            int grow = ybase + r, gcol = x0 + 2 * u;
            float f0 = 0.f, f1 = 0.f;
            if (grow < IMG) {
                const float* rp = x + (((size_t)b * CH_IN + c) * IMG + grow) * IMG;
                if (gcol < IMG) f0 = rp[gcol];
                if (gcol + 1 < IMG) f1 = rp[gcol + 1];
            }
            smem[idx] = (unsigned int)f2h_bits(f0) | ((unsigned int)f2h_bits(f1) << 16);
        }
    }
    __syncthreads();

    int l = tid & 63, w = tid >> 6;
    int n = l & 15, g = l >> 4;

    uint4 at[6];
    #pragma unroll
    for (int s = 0; s < 6; ++s) at[s] = afrag[s * 64 + l];

    int rowb[6];
    #pragma unroll
    for (int s = 0; s < 6; ++s) {
        int oct = s * 4 + g;
        int c = oct >> 3, ky = oct & 7;
        rowb[s] = (c * SROWS + n + ky) * (PITCH_DW * 4) + w * 64;
    }

    float bias_[4];
    {
        int ob = (g & 1) * 4;
        #pragma unroll
        for (int r2 = 0; r2 < 4; ++r2) bias_[r2] = conv_b[ob + r2];
    }
    bool rowok = (ybase + n) < CONV_OUT;
    int dlt = g >> 1;
    float sums[4] = {0.f, 0.f, 0.f, 0.f};
    const char* sb = (const char*)smem;

    #pragma unroll
    for (int u = 0; u < 4; ++u) {
        f32x4_t acc[4];
        #pragma unroll
        for (int d = 0; d < 4; ++d) acc[d] = (f32x4_t){0.f, 0.f, 0.f, 0.f};

        #pragma unroll
        for (int s = 0; s < 6; ++s) {
            uint4 lo = *(const uint4*)(sb + rowb[s] + (u << 4));
            uint4 hi = *(const uint4*)(sb + rowb[s] + (u << 4) + 16);
            unsigned int eu[8] = {lo.x, lo.y, lo.z, lo.w, hi.x, hi.y, hi.z, hi.w};
            half8_t a;
            __builtin_memcpy(&a, &at[s], 16);
            #pragma unroll
            for (int d = 0; d < 4; ++d) {
                uint4 bu = make_uint4(eu[d], eu[d + 1], eu[d + 2], eu[d + 3]);
                half8_t bf;
                __builtin_memcpy(&bf, &bu, 16);
                acc[d] = __builtin_amdgcn_mfma_f32_16x16x32_f16(a, bf, acc[d], 0, 0, 0);
            }
        }

        #pragma unroll
        for (int d = 0; d < 4; ++d) {
            int col = x0 + 32 * w + 8 * u + 2 * d + dlt;
            bool colok = col < CONV_OUT;
            #pragma unroll
            for (int r2 = 0; r2 < 4; ++r2) {
                float v = acc[d][r2] + bias_[r2];
                v = v > 0.f ? v : 0.f;
                sums[r2] += (rowok && colok) ? v : 0.f;
            }
        }
    }

    #pragma unroll
    for (int r2 = 0; r2 < 4; ++r2) {
        sums[r2] += __shfl_xor(sums[r2], 1, 64);
        sums[r2] += __shfl_xor(sums[r2], 2, 64);
        sums[r2] += __shfl_xor(sums[r2], 4, 64);
        sums[r2] += __shfl_xor(sums[r2], 8, 64);
        sums[r2] += __shfl_xor(sums[r2], 32, 64);
    }
    if (l == 0) {
        #pragma unroll
        for (int r2 = 0; r2 < 4; ++r2) red[w][r2] = sums[r2];
    }
    if (l == 16) {
        #pragma unroll
        for (int r2 = 0; r2 < 4; ++r2) red[w][4 + r2] = sums[r2];
    }
    __syncthreads();
    if (tid < CH_OUT) {
        float s = red[0][tid] + red[1][tid] + red[2][tid] + red[3][tid];
        partial[(b * TILES_PER_B + stripe * 4 + chunk) * CH_OUT + tid] = s;
    }
}

// ---------------------------------------------------------------------------
// Kernel 2: pooled mean + FC -> pred, TPS system, pivoted LU solve (double).
// ---------------------------------------------------------------------------
__device__ __forceinline__ double ctrl_lin(int i) { return -1.0 + (2.0 / 3.0) * i; }

__global__ void solve_kernel(const float* __restrict__ partial,
                             const float* __restrict__ fc_w,
                             const float* __restrict__ fc_b,
                             float* __restrict__ Wf) {
    __shared__ double L[19][19];
    __shared__ double Ys[19][64];
    __shared__ double piv_fac[19];
    __shared__ int piv_idx;
    __shared__ float pooledS[BATCH][CH_OUT];

    int t = threadIdx.x;

    for (int p = t; p < BATCH * CH_OUT; p += 64) {
        int b = p >> 3, o = p & 7;
        double s = 0.0;
        for (int tt = 0; tt < TILES_PER_B; ++tt)
            s += (double)partial[(b * TILES_PER_B + tt) * CH_OUT + o];
        pooledS[b][o] = (float)(s / ((double)CONV_OUT * (double)CONV_OUT));
    }
    __syncthreads();

    {
        int b = t >> 1, c = t & 1;
        for (int k = 0; k < KPTS; ++k) {
            int j = k * 2 + c;
            double s = (double)fc_b[j];
            for (int o = 0; o < CH_OUT; ++o)
                s += (double)pooledS[b][o] * (double)fc_w[j * CH_OUT + o];
            Ys[k][t] = s;
        }
        for (int k = KPTS; k < 19; ++k) Ys[k][t] = 0.0;
    }

    for (int p = t; p < 19 * 19; p += 64) {
        int r = p / 19, cc = p % 19;
        double v;
        if (r < KPTS && cc < KPTS) {
            double dx = ctrl_lin(r & 3) - ctrl_lin(cc & 3);
            double dy = ctrl_lin(r >> 2) - ctrl_lin(cc >> 2);
            double d2 = dx * dx + dy * dy;
            v = d2 * log(d2 + 1e-6);
        } else if (r < KPTS) {
            v = (cc == KPTS) ? 1.0 : (cc == KPTS + 1 ? ctrl_lin(r & 3) : ctrl_lin(r >> 2));
        } else if (cc < KPTS) {
            v = (r == KPTS) ? 1.0 : (r == KPTS + 1 ? ctrl_lin(cc & 3) : ctrl_lin(cc >> 2));
        } else v = 0.0;
        L[r][cc] = v;
    }
    __syncthreads();

    for (int k = 0; k < 19; ++k) {
        if (t == 0) {
            int pi = k; double mx = fabs(L[k][k]);
            for (int i = k + 1; i < 19; ++i) {
                double a = fabs(L[i][k]);
                if (a > mx) { mx = a; pi = i; }
            }
            piv_idx = pi;
        }
        __syncthreads();
        int pi = piv_idx;
        if (pi != k) {
            if (t < 19) { double tmp = L[k][t]; L[k][t] = L[pi][t]; L[pi][t] = tmp; }
            { double tmp = Ys[k][t]; Ys[k][t] = Ys[pi][t]; Ys[pi][t] = tmp; }
        }
        __syncthreads();
        if (t > k && t < 19) piv_fac[t] = L[t][k] / L[k][k];
        __syncthreads();
        if (t > k && t < 19) {
            double lkj = L[k][t];
            for (int i = k + 1; i < 19; ++i) L[i][t] -= piv_fac[i] * lkj;
        }
        {
            double ykt = Ys[k][t];
            for (int i = k + 1; i < 19; ++i) Ys[i][t] -= piv_fac[i] * ykt;
        }
        __syncthreads();
    }

    for (int k = 18; k >= 0; --k) {
        double s = Ys[k][t];
        for (int j = k + 1; j < 19; ++j) s -= L[k][j] * Ys[j][t];
        Ys[k][t] = s / L[k][k];
    }

    {
        int b = t >> 1, c = t & 1;
        for (int k = 0; k < 19; ++k)
            Wf[(b * 19 + k) * 2 + c] = (float)Ys[k][t];
    }
}

// ---------------------------------------------------------------------------
// Kernel 3: fused TPS grid evaluation + bilinear grid_sample (zero padding).
// H16=true: gather from f16 image (half the fetch bytes).
// ---------------------------------------------------------------------------
template <bool H16>
__global__ __launch_bounds__(256)
void tps_sample_kernel(const float* __restrict__ x, const unsigned short* __restrict__ xh,
                       const float* __restrict__ Wf, float* __restrict__ out) {
    int blk = blockIdx.x;
    int b = blk >> 10;
    int pix = ((blk & 1023) << 8) | threadIdx.x;
    int i = pix >> 9, j = pix & 511;

    const float* Wb = Wf + b * 38;

    float gx = -1.f + (2.f / 511.f) * (float)j;
    float gy = -1.f + (2.f / 511.f) * (float)i;

    float mx = Wb[32] + gx * Wb[34] + gy * Wb[36];
    float my = Wb[33] + gx * Wb[35] + gy * Wb[37];
    #pragma unroll
    for (int k = 0; k < KPTS; ++k) {
        float sx = -1.f + (2.f / 3.f) * (float)(k & 3);
        float sy = -1.f + (2.f / 3.f) * (float)(k >> 2);
        float dx = gx - sx, dy = gy - sy;
        float d2 = dx * dx + dy * dy;
        float u = d2 * (0.69314718055994531f * __log2f(d2 + 1e-6f));
        mx += u * Wb[2 * k];
        my += u * Wb[2 * k + 1];
    }

    float ix = (mx + 1.f) * 256.f - 0.5f;
    float iy = (my + 1.f) * 256.f - 0.5f;
    float x0f = floorf(ix), y0f = floorf(iy);
    int x0 = (int)x0f, y0 = (int)y0f;
    int x1 = x0 + 1, y1 = y0 + 1;
    float wx1 = ix - x0f, wy1 = iy - y0f;
    float wx0 = 1.f - wx1, wy0 = 1.f - wy1;

    bool vx0 = (x0 >= 0) & (x0 < IMG), vx1 = (x1 >= 0) & (x1 < IMG);
    bool vy0 = (y0 >= 0) & (y0 < IMG), vy1 = (y1 >= 0) & (y1 < IMG);
    int xc0 = min(max(x0, 0), IMG - 1), xc1 = min(max(x1, 0), IMG - 1);
    int yc0 = min(max(y0, 0), IMG - 1), yc1 = min(max(y1, 0), IMG - 1);

    float w00 = (vy0 && vx0) ? wy0 * wx0 : 0.f;
    float w01 = (vy0 && vx1) ? wy0 * wx1 : 0.f;
    float w10 = (vy1 && vx0) ? wy1 * wx0 : 0.f;
    float w11 = (vy1 && vx1) ? wy1 * wx1 : 0.f;

    int o00 = yc0 * IMG + xc0, o01 = yc0 * IMG + xc1;
    int o10 = yc1 * IMG + xc0, o11 = yc1 * IMG + xc1;

    #pragma unroll
    for (int c = 0; c < CH_IN; ++c) {
        float v;
        if (H16) {
            const unsigned short* xp = xh + ((size_t)b * CH_IN + c) * IMG * IMG;
            v = h2f_bits(xp[o00]) * w00 + h2f_bits(xp[o01]) * w01
              + h2f_bits(xp[o10]) * w10 + h2f_bits(xp[o11]) * w11;
        } else {
            const float* xp = x + ((size_t)b * CH_IN + c) * IMG * IMG;
            v = xp[o00] * w00 + xp[o01] * w01 + xp[o10] * w10 + xp[o11] * w11;
        }
        out[(((size_t)b * CH_IN + c) << 18) + (i << 9) + j] = v;
    }
}

// ---------------------------------------------------------------------------
extern "C" void kernel_launch(void* const* d_in, const int* in_sizes, int n_in,
                              void* d_out, int out_size, void* d_ws, size_t ws_size,
                              hipStream_t stream) {
    const float* x      = (const float*)d_in[0];
    const float* conv_w = (const float*)d_in[1];
    const float* conv_b = (const float*)d_in[2];
    const float* fc_w   = (const float*)d_in[3];
    const float* fc_b   = (const float*)d_in[4];
    float* out = (float*)d_out;

    char* ws = (char*)d_ws;
    uint4* afrag   = (uint4*)ws;                          // 6 KB @ 0
    float* partial = (float*)(ws + 8192);                 // 128 KB
    float* Wf      = (float*)(ws + 139264);               // 4.8 KB
    unsigned short* xh = (unsigned short*)(ws + 147456);  // 48 MB f16 image
    const size_t need = 147456 + (size_t)BATCH * CH_IN * IMG * IMG * 2;
    bool useH16 = ws_size >= need;

    wprep_kernel<<<dim3(2), dim3(256), 0, stream>>>(conv_w, afrag);
    if (useH16) {
        h16_kernel<<<dim3(4096), dim3(256), 0, stream>>>(x, (unsigned int*)xh);
        conv_pool_kernel<true><<<dim3(BATCH * TILES_PER_B), dim3(256), 0, stream>>>(
            x, xh, afrag, conv_b, partial);
    } else {
        conv_pool_kernel<false><<<dim3(BATCH * TILES_PER_B), dim3(256), 0, stream>>>(
            x, xh, afrag, conv_b, partial);
    }
    solve_kernel<<<dim3(1), dim3(64), 0, stream>>>(partial, fc_w, fc_b, Wf);
    if (useH16) {
        tps_sample_kernel<true><<<dim3(BATCH * 1024), dim3(256), 0, stream>>>(x, xh, Wf, out);
    } else {
        tps_sample_kernel<false><<<dim3(BATCH * 1024), dim3(256), 0, stream>>>(x, xh, Wf, out);
    }
}

// Round 6
// 162.772 us; speedup vs baseline: 1.7843x; 1.0548x over previous
//
#include <hip/hip_runtime.h>
#include <hip/hip_bf16.h>
#include <hip/hip_fp16.h>
#include <math.h>

// Problem constants
#define BATCH 32
#define CH_IN 3
#define CH_OUT 8
#define IMG 512
#define KSZ 7
#define CONV_OUT 506          // 512 - 6
#define KPTS 16
#define TILES_PER_B 128       // 32 row-stripes x 4 col-chunks

// Conv MFMA geometry
#define SROWS 23              // 16 out rows + 7 halo (ky pad to 8 -> max n+ky = 22)
#define PITCH_DW 76           // 152 f16 px per row = 304 bytes (16B aligned, 2-way banks)
#define SMEM_DW (CH_IN * SROWS * PITCH_DW)   // 5244 dwords = 21 KB

// Sampler: batches per block (4 block-groups x 8 = 32)
#define BPB 8

typedef _Float16 half8_t __attribute__((ext_vector_type(8)));
typedef float f32x4_t __attribute__((ext_vector_type(4)));

__device__ __forceinline__ unsigned short f2h_bits(float f) {
    _Float16 h = (_Float16)f;
    unsigned short u;
    __builtin_memcpy(&u, &h, 2);
    return u;
}
__device__ __forceinline__ float h2f_bits(unsigned short u) {
    _Float16 h;
    __builtin_memcpy(&h, &u, 2);
    return (float)h;
}

// ---------------------------------------------------------------------------
// Kernel h16: one-pass f32 -> f16 image conversion (memory-bound).
// ---------------------------------------------------------------------------
__global__ __launch_bounds__(256)
void h16_kernel(const float* __restrict__ x, unsigned int* __restrict__ xh) {
    const int total4 = BATCH * CH_IN * IMG * IMG / 4;   // 6291456
    int stride = gridDim.x * 256;
    for (int p = blockIdx.x * 256 + threadIdx.x; p < total4; p += stride) {
        float4 v = ((const float4*)x)[p];
        unsigned int lo = (unsigned int)f2h_bits(v.x) | ((unsigned int)f2h_bits(v.y) << 16);
        unsigned int hi = (unsigned int)f2h_bits(v.z) | ((unsigned int)f2h_bits(v.w) << 16);
        xh[2 * p] = lo;
        xh[2 * p + 1] = hi;
    }
}

// ---------------------------------------------------------------------------
// Kernel 0: precompute MFMA A-fragment table Afrag[s][lane] (uint4 = 8 f16).
// ---------------------------------------------------------------------------
__global__ void wprep_kernel(const float* __restrict__ w, uint4* __restrict__ afrag) {
    int idx = blockIdx.x * 256 + threadIdx.x;
    if (idx >= 6 * 64) return;
    int s = idx >> 6, l = idx & 63;
    int m = l & 15;
    int dlt = m >> 3, o = m & 7;
    int oct = s * 4 + (l >> 4);
    int c = oct >> 3, ky = oct & 7;
    unsigned short h[8];
    #pragma unroll
    for (int j = 0; j < 8; ++j) {
        int kx = j - dlt;
        float v = 0.f;
        if (ky < KSZ && kx >= 0 && kx < KSZ)
            v = w[((o * CH_IN + c) * KSZ + ky) * KSZ + kx];
        h[j] = f2h_bits(v);
    }
    uint4 out;
    __builtin_memcpy(&out, h, 16);
    afrag[idx] = out;
}

// ---------------------------------------------------------------------------
// Kernel 1: conv 7x7 + bias + relu + masked spatial sum via MFMA 16x16x32 f16.
// ---------------------------------------------------------------------------
template <bool H16>
__global__ __launch_bounds__(256)
void conv_pool_kernel(const float* __restrict__ x, const unsigned short* __restrict__ xh,
                      const uint4* __restrict__ afrag, const float* __restrict__ conv_b,
                      float* __restrict__ partial) {
    __shared__ unsigned int smem[SMEM_DW];
    __shared__ float red[4][8];

    int blk = blockIdx.x;
    int b = blk >> 7;
    int stripe = (blk >> 2) & 31;
    int chunk = blk & 3;
    int ybase = stripe * 16;
    int x0 = chunk * 128;
    int tid = threadIdx.x;

    if (H16) {
        const unsigned short* xhb = xh + (size_t)b * CH_IN * IMG * IMG;
        for (int idx4 = tid; idx4 < SMEM_DW / 4; idx4 += 256) {
            int c = idx4 / (SROWS * 19);
            int rem = idx4 - c * (SROWS * 19);
            int r = rem / 19;
            int u4 = rem - r * 19;
            int grow = ybase + r;
            int gcol = x0 + (u4 << 3);
            uint4 v = make_uint4(0u, 0u, 0u, 0u);
            if (grow < IMG) {
                const unsigned short* rp = xhb + ((size_t)c * IMG + grow) * IMG;
                if (gcol + 8 <= IMG) {
                    v = *(const uint4*)(rp + gcol);
                } else {
                    unsigned short h[8] = {0, 0, 0, 0, 0, 0, 0, 0};
                    #pragma unroll
                    for (int j = 0; j < 8; ++j) {
                        int cc = gcol + j;
                        if (cc < IMG) h[j] = rp[cc];
                    }
                    __builtin_memcpy(&v, h, 16);
                }
            }
            ((uint4*)smem)[idx4] = v;
        }
    } else {
        for (int idx = tid; idx < SMEM_DW; idx += 256) {
            int c = idx / (SROWS * PITCH_DW);
            int rem = idx - c * (SROWS * PITCH_DW);
            int r = rem / PITCH_DW;
            int u = rem - r * PITCH_DW;
            int grow = ybase + r, gcol = x0 + 2 * u;
            float f0 = 0.f, f1 = 0.f;
            if (grow < IMG) {
                const float* rp = x + (((size_t)b * CH_IN + c) * IMG + grow) * IMG;
                if (gcol < IMG) f0 = rp[gcol];
                if (gcol + 1 < IMG) f1 = rp[gcol + 1];
            }
            smem[idx] = (unsigned int)f2h_bits(f0) | ((unsigned int)f2h_bits(f1) << 16);
        }
    }
    __syncthreads();

    int l = tid & 63, w = tid >> 6;
    int n = l & 15, g = l >> 4;

    uint4 at[6];
    #pragma unroll
    for (int s = 0; s < 6; ++s) at[s] = afrag[s * 64 + l];

    int rowb[6];
    #pragma unroll
    for (int s = 0; s < 6; ++s) {
        int oct = s * 4 + g;
        int c = oct >> 3, ky = oct & 7;
        rowb[s] = (c * SROWS + n + ky) * (PITCH_DW * 4) + w * 64;
    }

    float bias_[4];
    {
        int ob = (g & 1) * 4;
        #pragma unroll
        for (int r2 = 0; r2 < 4; ++r2) bias_[r2] = conv_b[ob + r2];
    }
    bool rowok = (ybase + n) < CONV_OUT;
    int dlt = g >> 1;
    float sums[4] = {0.f, 0.f, 0.f, 0.f};
    const char* sb = (const char*)smem;

    #pragma unroll
    for (int u = 0; u < 4; ++u) {
        f32x4_t acc[4];
        #pragma unroll
        for (int d = 0; d < 4; ++d) acc[d] = (f32x4_t){0.f, 0.f, 0.f, 0.f};

        #pragma unroll
        for (int s = 0; s < 6; ++s) {
            uint4 lo = *(const uint4*)(sb + rowb[s] + (u << 4));
            uint4 hi = *(const uint4*)(sb + rowb[s] + (u << 4) + 16);
            unsigned int eu[8] = {lo.x, lo.y, lo.z, lo.w, hi.x, hi.y, hi.z, hi.w};
            half8_t a;
            __builtin_memcpy(&a, &at[s], 16);
            #pragma unroll
            for (int d = 0; d < 4; ++d) {
                uint4 bu = make_uint4(eu[d], eu[d + 1], eu[d + 2], eu[d + 3]);
                half8_t bf;
                __builtin_memcpy(&bf, &bu, 16);
                acc[d] = __builtin_amdgcn_mfma_f32_16x16x32_f16(a, bf, acc[d], 0, 0, 0);
            }
        }

        #pragma unroll
        for (int d = 0; d < 4; ++d) {
            int col = x0 + 32 * w + 8 * u + 2 * d + dlt;
            bool colok = col < CONV_OUT;
            #pragma unroll
            for (int r2 = 0; r2 < 4; ++r2) {
                float v = acc[d][r2] + bias_[r2];
                v = v > 0.f ? v : 0.f;
                sums[r2] += (rowok && colok) ? v : 0.f;
            }
        }
    }

    #pragma unroll
    for (int r2 = 0; r2 < 4; ++r2) {
        sums[r2] += __shfl_xor(sums[r2], 1, 64);
        sums[r2] += __shfl_xor(sums[r2], 2, 64);
        sums[r2] += __shfl_xor(sums[r2], 4, 64);
        sums[r2] += __shfl_xor(sums[r2], 8, 64);
        sums[r2] += __shfl_xor(sums[r2], 32, 64);
    }
    if (l == 0) {
        #pragma unroll
        for (int r2 = 0; r2 < 4; ++r2) red[w][r2] = sums[r2];
    }
    if (l == 16) {
        #pragma unroll
        for (int r2 = 0; r2 < 4; ++r2) red[w][4 + r2] = sums[r2];
    }
    __syncthreads();
    if (tid < CH_OUT) {
        float s = red[0][tid] + red[1][tid] + red[2][tid] + red[3][tid];
        partial[(b * TILES_PER_B + stripe * 4 + chunk) * CH_OUT + tid] = s;
    }
}

// ---------------------------------------------------------------------------
// Kernel 2: pooled mean + FC -> pred, TPS system, pivoted LU solve (double).
// ---------------------------------------------------------------------------
__device__ __forceinline__ double ctrl_lin(int i) { return -1.0 + (2.0 / 3.0) * i; }

__global__ void solve_kernel(const float* __restrict__ partial,
                             const float* __restrict__ fc_w,
                             const float* __restrict__ fc_b,
                             float* __restrict__ Wf) {
    __shared__ double L[19][19];
    __shared__ double Ys[19][64];
    __shared__ double piv_fac[19];
    __shared__ int piv_idx;
    __shared__ float pooledS[BATCH][CH_OUT];

    int t = threadIdx.x;

    for (int p = t; p < BATCH * CH_OUT; p += 64) {
        int b = p >> 3, o = p & 7;
        double s = 0.0;
        for (int tt = 0; tt < TILES_PER_B; ++tt)
            s += (double)partial[(b * TILES_PER_B + tt) * CH_OUT + o];
        pooledS[b][o] = (float)(s / ((double)CONV_OUT * (double)CONV_OUT));
    }
    __syncthreads();

    {
        int b = t >> 1, c = t & 1;
        for (int k = 0; k < KPTS; ++k) {
            int j = k * 2 + c;
            double s = (double)fc_b[j];
            for (int o = 0; o < CH_OUT; ++o)
                s += (double)pooledS[b][o] * (double)fc_w[j * CH_OUT + o];
            Ys[k][t] = s;
        }
        for (int k = KPTS; k < 19; ++k) Ys[k][t] = 0.0;
    }

    for (int p = t; p < 19 * 19; p += 64) {
        int r = p / 19, cc = p % 19;
        double v;
        if (r < KPTS && cc < KPTS) {
            double dx = ctrl_lin(r & 3) - ctrl_lin(cc & 3);
            double dy = ctrl_lin(r >> 2) - ctrl_lin(cc >> 2);
            double d2 = dx * dx + dy * dy;
            v = d2 * log(d2 + 1e-6);
        } else if (r < KPTS) {
            v = (cc == KPTS) ? 1.0 : (cc == KPTS + 1 ? ctrl_lin(r & 3) : ctrl_lin(r >> 2));
        } else if (cc < KPTS) {
            v = (r == KPTS) ? 1.0 : (r == KPTS + 1 ? ctrl_lin(cc & 3) : ctrl_lin(cc >> 2));
        } else v = 0.0;
        L[r][cc] = v;
    }
    __syncthreads();

    for (int k = 0; k < 19; ++k) {
        if (t == 0) {
            int pi = k; double mx = fabs(L[k][k]);
            for (int i = k + 1; i < 19; ++i) {
                double a = fabs(L[i][k]);
                if (a > mx) { mx = a; pi = i; }
            }
            piv_idx = pi;
        }
        __syncthreads();
        int pi = piv_idx;
        if (pi != k) {
            if (t < 19) { double tmp = L[k][t]; L[k][t] = L[pi][t]; L[pi][t] = tmp; }
            { double tmp = Ys[k][t]; Ys[k][t] = Ys[pi][t]; Ys[pi][t] = tmp; }
        }
        __syncthreads();
        if (t > k && t < 19) piv_fac[t] = L[t][k] / L[k][k];
        __syncthreads();
        if (t > k && t < 19) {
            double lkj = L[k][t];
            for (int i = k + 1; i < 19; ++i) L[i][t] -= piv_fac[i] * lkj;
        }
        {
            double ykt = Ys[k][t];
            for (int i = k + 1; i < 19; ++i) Ys[i][t] -= piv_fac[i] * ykt;
        }
        __syncthreads();
    }

    for (int k = 18; k >= 0; --k) {
        double s = Ys[k][t];
        for (int j = k + 1; j < 19; ++j) s -= L[k][j] * Ys[j][t];
        Ys[k][t] = s / L[k][k];
    }

    {
        int b = t >> 1, c = t & 1;
        for (int k = 0; k < 19; ++k)
            Wf[(b * 19 + k) * 2 + c] = (float)Ys[k][t];
    }
}

// ---------------------------------------------------------------------------
// Kernel 3: fused TPS grid + bilinear sample, batch-amortized basis.
// Thread = one output pixel; computes the 16 RBF basis values ONCE, then
// loops over BPB batches (W loads are wave-uniform -> scalar loads).
// ---------------------------------------------------------------------------
template <bool H16>
__global__ __launch_bounds__(256)
void tps_sample_kernel(const float* __restrict__ x, const unsigned short* __restrict__ xh,
                       const float* __restrict__ Wf, float* __restrict__ out) {
    int blk = blockIdx.x;
    int bgrp = blk >> 10;                     // 0..3 -> batches [8*bgrp, 8*bgrp+8)
    int pix = ((blk & 1023) << 8) | threadIdx.x;
    int i = pix >> 9, j = pix & 511;

    float gx = -1.f + (2.f / 511.f) * (float)j;
    float gy = -1.f + (2.f / 511.f) * (float)i;

    // batch-independent RBF basis
    float U[KPTS];
    #pragma unroll
    for (int k = 0; k < KPTS; ++k) {
        float sx = -1.f + (2.f / 3.f) * (float)(k & 3);
        float sy = -1.f + (2.f / 3.f) * (float)(k >> 2);
        float dx = gx - sx, dy = gy - sy;
        float d2 = dx * dx + dy * dy;
        U[k] = d2 * (0.69314718055994531f * __log2f(d2 + 1e-6f));
    }

    for (int b = bgrp * BPB; b < bgrp * BPB + BPB; ++b) {
        const float* Wb = Wf + b * 38;        // wave-uniform -> s_load

        float mx = Wb[32] + gx * Wb[34] + gy * Wb[36];
        float my = Wb[33] + gx * Wb[35] + gy * Wb[37];
        #pragma unroll
        for (int k = 0; k < KPTS; ++k) {
            mx += U[k] * Wb[2 * k];
            my += U[k] * Wb[2 * k + 1];
        }

        float ix = (mx + 1.f) * 256.f - 0.5f;
        float iy = (my + 1.f) * 256.f - 0.5f;
        float x0f = floorf(ix), y0f = floorf(iy);
        int x0 = (int)x0f, y0 = (int)y0f;
        int x1 = x0 + 1, y1 = y0 + 1;
        float wx1 = ix - x0f, wy1 = iy - y0f;
        float wx0 = 1.f - wx1, wy0 = 1.f - wy1;

        bool vx0 = (x0 >= 0) & (x0 < IMG), vx1 = (x1 >= 0) & (x1 < IMG);
        bool vy0 = (y0 >= 0) & (y0 < IMG), vy1 = (y1 >= 0) & (y1 < IMG);
        int xc0 = min(max(x0, 0), IMG - 1), xc1 = min(max(x1, 0), IMG - 1);
        int yc0 = min(max(y0, 0), IMG - 1), yc1 = min(max(y1, 0), IMG - 1);

        float w00 = (vy0 && vx0) ? wy0 * wx0 : 0.f;
        float w01 = (vy0 && vx1) ? wy0 * wx1 : 0.f;
        float w10 = (vy1 && vx0) ? wy1 * wx0 : 0.f;
        float w11 = (vy1 && vx1) ? wy1 * wx1 : 0.f;

        int o00 = yc0 * IMG + xc0, o01 = yc0 * IMG + xc1;
        int o10 = yc1 * IMG + xc0, o11 = yc1 * IMG + xc1;

        #pragma unroll
        for (int c = 0; c < CH_IN; ++c) {
            float v;
            if (H16) {
                const unsigned short* xp = xh + ((size_t)b * CH_IN + c) * IMG * IMG;
                v = h2f_bits(xp[o00]) * w00 + h2f_bits(xp[o01]) * w01
                  + h2f_bits(xp[o10]) * w10 + h2f_bits(xp[o11]) * w11;
            } else {
                const float* xp = x + ((size_t)b * CH_IN + c) * IMG * IMG;
                v = xp[o00] * w00 + xp[o01] * w01 + xp[o10] * w10 + xp[o11] * w11;
            }
            out[(((size_t)b * CH_IN + c) << 18) + (i << 9) + j] = v;
        }
    }
}

// ---------------------------------------------------------------------------
extern "C" void kernel_launch(void* const* d_in, const int* in_sizes, int n_in,
                              void* d_out, int out_size, void* d_ws, size_t ws_size,
                              hipStream_t stream) {
    const float* x      = (const float*)d_in[0];
    const float* conv_w = (const float*)d_in[1];
    const float* conv_b = (const float*)d_in[2];
    const float* fc_w   = (const float*)d_in[3];
    const float* fc_b   = (const float*)d_in[4];
    float* out = (float*)d_out;

    char* ws = (char*)d_ws;
    uint4* afrag   = (uint4*)ws;                          // 6 KB @ 0
    float* partial = (float*)(ws + 8192);                 // 128 KB
    float* Wf      = (float*)(ws + 139264);               // 4.8 KB
    unsigned short* xh = (unsigned short*)(ws + 147456);  // 48 MB f16 image
    const size_t need = 147456 + (size_t)BATCH * CH_IN * IMG * IMG * 2;
    bool useH16 = ws_size >= need;

    wprep_kernel<<<dim3(2), dim3(256), 0, stream>>>(conv_w, afrag);
    if (useH16) {
        h16_kernel<<<dim3(4096), dim3(256), 0, stream>>>(x, (unsigned int*)xh);
        conv_pool_kernel<true><<<dim3(BATCH * TILES_PER_B), dim3(256), 0, stream>>>(
            x, xh, afrag, conv_b, partial);
    } else {
        conv_pool_kernel<false><<<dim3(BATCH * TILES_PER_B), dim3(256), 0, stream>>>(
            x, xh, afrag, conv_b, partial);
    }
    solve_kernel<<<dim3(1), dim3(64), 0, stream>>>(partial, fc_w, fc_b, Wf);
    if (useH16) {
        tps_sample_kernel<true><<<dim3(4 * 1024), dim3(256), 0, stream>>>(x, xh, Wf, out);
    } else {
        tps_sample_kernel<false><<<dim3(4 * 1024), dim3(256), 0, stream>>>(x, xh, Wf, out);
    }
}

// Round 7
// 145.462 us; speedup vs baseline: 1.9966x; 1.1190x over previous
//
#include <hip/hip_runtime.h>
#include <hip/hip_bf16.h>
#include <hip/hip_fp16.h>
#include <math.h>

// Problem constants
#define BATCH 32
#define CH_IN 3
#define CH_OUT 8
#define IMG 512
#define KSZ 7
#define CONV_OUT 506          // 512 - 6
#define KPTS 16
#define TILES_PER_B 128       // 32 row-stripes x 4 col-chunks

// Conv MFMA geometry
#define SROWS 23              // 16 out rows + 7 halo (ky pad to 8 -> max n+ky = 22)
#define PITCH_DW 76           // 152 f16 px per row = 304 bytes (16B aligned, 2-way banks)
#define SMEM_DW (CH_IN * SROWS * PITCH_DW)   // 5244 dwords = 21 KB

// Sampler: batches per block (4 block-groups x 8 = 32)
#define BPB 8

typedef _Float16 half8_t __attribute__((ext_vector_type(8)));
typedef float f32x4_t __attribute__((ext_vector_type(4)));

__device__ __forceinline__ unsigned short f2h_bits(float f) {
    _Float16 h = (_Float16)f;
    unsigned short u;
    __builtin_memcpy(&u, &h, 2);
    return u;
}
__device__ __forceinline__ float h2f_bits(unsigned short u) {
    _Float16 h;
    __builtin_memcpy(&h, &u, 2);
    return (float)h;
}
__device__ __forceinline__ unsigned int pk2(float a, float b) {
    return (unsigned int)f2h_bits(a) | ((unsigned int)f2h_bits(b) << 16);
}

// ---------------------------------------------------------------------------
// Kernel 0: precompute MFMA A-fragment table Afrag[s][lane] (uint4 = 8 f16).
// ---------------------------------------------------------------------------
__global__ void wprep_kernel(const float* __restrict__ w, uint4* __restrict__ afrag) {
    int idx = blockIdx.x * 256 + threadIdx.x;
    if (idx >= 6 * 64) return;
    int s = idx >> 6, l = idx & 63;
    int m = l & 15;
    int dlt = m >> 3, o = m & 7;
    int oct = s * 4 + (l >> 4);
    int c = oct >> 3, ky = oct & 7;
    unsigned short h[8];
    #pragma unroll
    for (int j = 0; j < 8; ++j) {
        int kx = j - dlt;
        float v = 0.f;
        if (ky < KSZ && kx >= 0 && kx < KSZ)
            v = w[((o * CH_IN + c) * KSZ + ky) * KSZ + kx];
        h[j] = f2h_bits(v);
    }
    uint4 out;
    __builtin_memcpy(&out, h, 16);
    afrag[idx] = out;
}

// ---------------------------------------------------------------------------
// Kernel 1: conv 7x7 + bias + relu + masked spatial sum via MFMA 16x16x32 f16.
// FUSED=true: stage from f32 x, convert to f16 in-flight, and write the
// owned region of the f16 image xh (each pixel written by exactly one block).
// FUSED=false: fallback, stage f32->LDS only (no xh, sampler reads f32).
// partial layout: [o][b][tile] (contiguous per (b,o) for the solve reduce).
// ---------------------------------------------------------------------------
template <bool FUSED>
__global__ __launch_bounds__(256)
void conv_pool_kernel(const float* __restrict__ x, unsigned short* __restrict__ xh,
                      const uint4* __restrict__ afrag, const float* __restrict__ conv_b,
                      float* __restrict__ partial) {
    __shared__ unsigned int smem[SMEM_DW];
    __shared__ float red[4][8];

    int blk = blockIdx.x;
    int b = blk >> 7;
    int stripe = (blk >> 2) & 31;
    int chunk = blk & 3;
    int ybase = stripe * 16;
    int x0 = chunk * 128;
    int tid = threadIdx.x;

    if (FUSED) {
        const float* xb = x + (size_t)b * CH_IN * IMG * IMG;
        unsigned short* xhb = xh + (size_t)b * CH_IN * IMG * IMG;
        for (int idx4 = tid; idx4 < SMEM_DW / 4; idx4 += 256) {
            int c = idx4 / (SROWS * 19);
            int rem = idx4 - c * (SROWS * 19);
            int r = rem / 19;
            int u4 = rem - r * 19;
            int grow = ybase + r;
            int gcol = x0 + (u4 << 3);
            uint4 v = make_uint4(0u, 0u, 0u, 0u);
            if (grow < IMG && gcol < IMG) {   // chunks are always fully in or out
                const float* rp = xb + ((size_t)c * IMG + grow) * IMG + gcol;
                float4 f0 = *(const float4*)rp;
                float4 f1 = *(const float4*)(rp + 4);
                v.x = pk2(f0.x, f0.y);
                v.y = pk2(f0.z, f0.w);
                v.z = pk2(f1.x, f1.y);
                v.w = pk2(f1.z, f1.w);
            }
            ((uint4*)smem)[idx4] = v;
            if (r < 16 && u4 < 16)            // owner region: written exactly once
                *(uint4*)(xhb + ((size_t)c * IMG + grow) * IMG + gcol) = v;
        }
    } else {
        for (int idx = tid; idx < SMEM_DW; idx += 256) {
            int c = idx / (SROWS * PITCH_DW);
            int rem = idx - c * (SROWS * PITCH_DW);
            int r = rem / PITCH_DW;
            int u = rem - r * PITCH_DW;
            int grow = ybase + r, gcol = x0 + 2 * u;
            float f0 = 0.f, f1 = 0.f;
            if (grow < IMG) {
                const float* rp = x + (((size_t)b * CH_IN + c) * IMG + grow) * IMG;
                if (gcol < IMG) f0 = rp[gcol];
                if (gcol + 1 < IMG) f1 = rp[gcol + 1];
            }
            smem[idx] = pk2(f0, f1);
        }
    }
    __syncthreads();

    int l = tid & 63, w = tid >> 6;
    int n = l & 15, g = l >> 4;

    uint4 at[6];
    #pragma unroll
    for (int s = 0; s < 6; ++s) at[s] = afrag[s * 64 + l];

    int rowb[6];
    #pragma unroll
    for (int s = 0; s < 6; ++s) {
        int oct = s * 4 + g;
        int c = oct >> 3, ky = oct & 7;
        rowb[s] = (c * SROWS + n + ky) * (PITCH_DW * 4) + w * 64;
    }

    float bias_[4];
    {
        int ob = (g & 1) * 4;
        #pragma unroll
        for (int r2 = 0; r2 < 4; ++r2) bias_[r2] = conv_b[ob + r2];
    }
    bool rowok = (ybase + n) < CONV_OUT;
    int dlt = g >> 1;
    float sums[4] = {0.f, 0.f, 0.f, 0.f};
    const char* sb = (const char*)smem;

    #pragma unroll
    for (int u = 0; u < 4; ++u) {
        f32x4_t acc[4];
        #pragma unroll
        for (int d = 0; d < 4; ++d) acc[d] = (f32x4_t){0.f, 0.f, 0.f, 0.f};

        #pragma unroll
        for (int s = 0; s < 6; ++s) {
            uint4 lo = *(const uint4*)(sb + rowb[s] + (u << 4));
            uint4 hi = *(const uint4*)(sb + rowb[s] + (u << 4) + 16);
            unsigned int eu[8] = {lo.x, lo.y, lo.z, lo.w, hi.x, hi.y, hi.z, hi.w};
            half8_t a;
            __builtin_memcpy(&a, &at[s], 16);
            #pragma unroll
            for (int d = 0; d < 4; ++d) {
                uint4 bu = make_uint4(eu[d], eu[d + 1], eu[d + 2], eu[d + 3]);
                half8_t bf;
                __builtin_memcpy(&bf, &bu, 16);
                acc[d] = __builtin_amdgcn_mfma_f32_16x16x32_f16(a, bf, acc[d], 0, 0, 0);
            }
        }

        #pragma unroll
        for (int d = 0; d < 4; ++d) {
            int col = x0 + 32 * w + 8 * u + 2 * d + dlt;
            bool colok = col < CONV_OUT;
            #pragma unroll
            for (int r2 = 0; r2 < 4; ++r2) {
                float v = acc[d][r2] + bias_[r2];
                v = v > 0.f ? v : 0.f;
                sums[r2] += (rowok && colok) ? v : 0.f;
            }
        }
    }

    #pragma unroll
    for (int r2 = 0; r2 < 4; ++r2) {
        sums[r2] += __shfl_xor(sums[r2], 1, 64);
        sums[r2] += __shfl_xor(sums[r2], 2, 64);
        sums[r2] += __shfl_xor(sums[r2], 4, 64);
        sums[r2] += __shfl_xor(sums[r2], 8, 64);
        sums[r2] += __shfl_xor(sums[r2], 32, 64);
    }
    if (l == 0) {
        #pragma unroll
        for (int r2 = 0; r2 < 4; ++r2) red[w][r2] = sums[r2];
    }
    if (l == 16) {
        #pragma unroll
        for (int r2 = 0; r2 < 4; ++r2) red[w][4 + r2] = sums[r2];
    }
    __syncthreads();
    if (tid < CH_OUT) {
        float s = red[0][tid] + red[1][tid] + red[2][tid] + red[3][tid];
        // [o][b][tile] layout: contiguous 128-float runs per (b,o) for solve
        partial[tid * (BATCH * TILES_PER_B) + b * TILES_PER_B + stripe * 4 + chunk] = s;
    }
}

// ---------------------------------------------------------------------------
// Kernel 2: pooled mean (ILP float4 reduce) + FC -> pred, TPS system,
// pivoted LU solve (double), emit Wmat as float [32][19][2]. 64 threads.
// ---------------------------------------------------------------------------
__device__ __forceinline__ double ctrl_lin(int i) { return -1.0 + (2.0 / 3.0) * i; }

__global__ void solve_kernel(const float* __restrict__ partial,
                             const float* __restrict__ fc_w,
                             const float* __restrict__ fc_b,
                             float* __restrict__ Wf) {
    __shared__ double L[19][19];
    __shared__ double Ys[19][64];
    __shared__ double piv_fac[19];
    __shared__ int piv_idx;
    __shared__ float pooledS[BATCH][CH_OUT];

    int t = threadIdx.x;

    // pooled mean: [o][b][tile] -> contiguous 128 floats per (b,o); 4-way ILP
    for (int p = t; p < BATCH * CH_OUT; p += 64) {
        int b = p >> 3, o = p & 7;
        const float4* pp = (const float4*)(partial + o * (BATCH * TILES_PER_B) + b * TILES_PER_B);
        double a0 = 0.0, a1 = 0.0, a2 = 0.0, a3 = 0.0;
        #pragma unroll
        for (int gq = 0; gq < TILES_PER_B / 4; ++gq) {
            float4 v = pp[gq];
            a0 += (double)v.x; a1 += (double)v.y;
            a2 += (double)v.z; a3 += (double)v.w;
        }
        pooledS[b][o] = (float)(((a0 + a1) + (a2 + a3)) / ((double)CONV_OUT * (double)CONV_OUT));
    }
    __syncthreads();

    {
        int b = t >> 1, c = t & 1;
        for (int k = 0; k < KPTS; ++k) {
            int j = k * 2 + c;
            double s = (double)fc_b[j];
            for (int o = 0; o < CH_OUT; ++o)
                s += (double)pooledS[b][o] * (double)fc_w[j * CH_OUT + o];
            Ys[k][t] = s;
        }
        for (int k = KPTS; k < 19; ++k) Ys[k][t] = 0.0;
    }

    for (int p = t; p < 19 * 19; p += 64) {
        int r = p / 19, cc = p % 19;
        double v;
        if (r < KPTS && cc < KPTS) {
            double dx = ctrl_lin(r & 3) - ctrl_lin(cc & 3);
            double dy = ctrl_lin(r >> 2) - ctrl_lin(cc >> 2);
            double d2 = dx * dx + dy * dy;
            v = d2 * log(d2 + 1e-6);
        } else if (r < KPTS) {
            v = (cc == KPTS) ? 1.0 : (cc == KPTS + 1 ? ctrl_lin(r & 3) : ctrl_lin(r >> 2));
        } else if (cc < KPTS) {
            v = (r == KPTS) ? 1.0 : (r == KPTS + 1 ? ctrl_lin(cc & 3) : ctrl_lin(cc >> 2));
        } else v = 0.0;
        L[r][cc] = v;
    }
    __syncthreads();

    for (int k = 0; k < 19; ++k) {
        if (t == 0) {
            int pi = k; double mx = fabs(L[k][k]);
            for (int i = k + 1; i < 19; ++i) {
                double a = fabs(L[i][k]);
                if (a > mx) { mx = a; pi = i; }
            }
            piv_idx = pi;
        }
        __syncthreads();
        int pi = piv_idx;
        if (pi != k) {
            if (t < 19) { double tmp = L[k][t]; L[k][t] = L[pi][t]; L[pi][t] = tmp; }
            { double tmp = Ys[k][t]; Ys[k][t] = Ys[pi][t]; Ys[pi][t] = tmp; }
        }
        __syncthreads();
        if (t > k && t < 19) piv_fac[t] = L[t][k] / L[k][k];
        __syncthreads();
        if (t > k && t < 19) {
            double lkj = L[k][t];
            for (int i = k + 1; i < 19; ++i) L[i][t] -= piv_fac[i] * lkj;
        }
        {
            double ykt = Ys[k][t];
            for (int i = k + 1; i < 19; ++i) Ys[i][t] -= piv_fac[i] * ykt;
        }
        __syncthreads();
    }

    for (int k = 18; k >= 0; --k) {
        double s = Ys[k][t];
        for (int j = k + 1; j < 19; ++j) s -= L[k][j] * Ys[j][t];
        Ys[k][t] = s / L[k][k];
    }

    {
        int b = t >> 1, c = t & 1;
        for (int k = 0; k < 19; ++k)
            Wf[(b * 19 + k) * 2 + c] = (float)Ys[k][t];
    }
}

// ---------------------------------------------------------------------------
// Kernel 3: fused TPS grid + bilinear sample, batch-amortized basis.
// ---------------------------------------------------------------------------
template <bool H16>
__global__ __launch_bounds__(256)
void tps_sample_kernel(const float* __restrict__ x, const unsigned short* __restrict__ xh,
                       const float* __restrict__ Wf, float* __restrict__ out) {
    int blk = blockIdx.x;
    int bgrp = blk >> 10;                     // 0..3 -> batches [8*bgrp, 8*bgrp+8)
    int pix = ((blk & 1023) << 8) | threadIdx.x;
    int i = pix >> 9, j = pix & 511;

    float gx = -1.f + (2.f / 511.f) * (float)j;
    float gy = -1.f + (2.f / 511.f) * (float)i;

    float U[KPTS];
    #pragma unroll
    for (int k = 0; k < KPTS; ++k) {
        float sx = -1.f + (2.f / 3.f) * (float)(k & 3);
        float sy = -1.f + (2.f / 3.f) * (float)(k >> 2);
        float dx = gx - sx, dy = gy - sy;
        float d2 = dx * dx + dy * dy;
        U[k] = d2 * (0.69314718055994531f * __log2f(d2 + 1e-6f));
    }

    for (int b = bgrp * BPB; b < bgrp * BPB + BPB; ++b) {
        const float* Wb = Wf + b * 38;        // wave-uniform -> s_load

        float mx = Wb[32] + gx * Wb[34] + gy * Wb[36];
        float my = Wb[33] + gx * Wb[35] + gy * Wb[37];
        #pragma unroll
        for (int k = 0; k < KPTS; ++k) {
            mx += U[k] * Wb[2 * k];
            my += U[k] * Wb[2 * k + 1];
        }

        float ix = (mx + 1.f) * 256.f - 0.5f;
        float iy = (my + 1.f) * 256.f - 0.5f;
        float x0f = floorf(ix), y0f = floorf(iy);
        int x0 = (int)x0f, y0 = (int)y0f;
        int x1 = x0 + 1, y1 = y0 + 1;
        float wx1 = ix - x0f, wy1 = iy - y0f;
        float wx0 = 1.f - wx1, wy0 = 1.f - wy1;

        bool vx0 = (x0 >= 0) & (x0 < IMG), vx1 = (x1 >= 0) & (x1 < IMG);
        bool vy0 = (y0 >= 0) & (y0 < IMG), vy1 = (y1 >= 0) & (y1 < IMG);
        int xc0 = min(max(x0, 0), IMG - 1), xc1 = min(max(x1, 0), IMG - 1);
        int yc0 = min(max(y0, 0), IMG - 1), yc1 = min(max(y1, 0), IMG - 1);

        float w00 = (vy0 && vx0) ? wy0 * wx0 : 0.f;
        float w01 = (vy0 && vx1) ? wy0 * wx1 : 0.f;
        float w10 = (vy1 && vx0) ? wy1 * wx0 : 0.f;
        float w11 = (vy1 && vx1) ? wy1 * wx1 : 0.f;

        int o00 = yc0 * IMG + xc0, o01 = yc0 * IMG + xc1;
        int o10 = yc1 * IMG + xc0, o11 = yc1 * IMG + xc1;

        #pragma unroll
        for (int c = 0; c < CH_IN; ++c) {
            float v;
            if (H16) {
                const unsigned short* xp = xh + ((size_t)b * CH_IN + c) * IMG * IMG;
                v = h2f_bits(xp[o00]) * w00 + h2f_bits(xp[o01]) * w01
                  + h2f_bits(xp[o10]) * w10 + h2f_bits(xp[o11]) * w11;
            } else {
                const float* xp = x + ((size_t)b * CH_IN + c) * IMG * IMG;
                v = xp[o00] * w00 + xp[o01] * w01 + xp[o10] * w10 + xp[o11] * w11;
            }
            out[(((size_t)b * CH_IN + c) << 18) + (i << 9) + j] = v;
        }
    }
}

// ---------------------------------------------------------------------------
extern "C" void kernel_launch(void* const* d_in, const int* in_sizes, int n_in,
                              void* d_out, int out_size, void* d_ws, size_t ws_size,
                              hipStream_t stream) {
    const float* x      = (const float*)d_in[0];
    const float* conv_w = (const float*)d_in[1];
    const float* conv_b = (const float*)d_in[2];
    const float* fc_w   = (const float*)d_in[3];
    const float* fc_b   = (const float*)d_in[4];
    float* out = (float*)d_out;

    char* ws = (char*)d_ws;
    uint4* afrag   = (uint4*)ws;                          // 6 KB @ 0
    float* partial = (float*)(ws + 8192);                 // 128 KB
    float* Wf      = (float*)(ws + 139264);               // 4.8 KB
    unsigned short* xh = (unsigned short*)(ws + 147456);  // 48 MB f16 image
    const size_t need = 147456 + (size_t)BATCH * CH_IN * IMG * IMG * 2;
    bool fused = ws_size >= need;

    wprep_kernel<<<dim3(2), dim3(256), 0, stream>>>(conv_w, afrag);
    if (fused) {
        conv_pool_kernel<true><<<dim3(BATCH * TILES_PER_B), dim3(256), 0, stream>>>(
            x, xh, afrag, conv_b, partial);
    } else {
        conv_pool_kernel<false><<<dim3(BATCH * TILES_PER_B), dim3(256), 0, stream>>>(
            x, xh, afrag, conv_b, partial);
    }
    solve_kernel<<<dim3(1), dim3(64), 0, stream>>>(partial, fc_w, fc_b, Wf);
    if (fused) {
        tps_sample_kernel<true><<<dim3(4 * 1024), dim3(256), 0, stream>>>(x, xh, Wf, out);
    } else {
        tps_sample_kernel<false><<<dim3(4 * 1024), dim3(256), 0, stream>>>(x, xh, Wf, out);
    }
}